// Round 1
// baseline (589.611 us; speedup 1.0000x reference)
//
#include <hip/hip_runtime.h>

#define B_ 16
#define S_ 2048
#define D_ 512
#define MTOT (B_ * S_)

typedef _Float16 half8 __attribute__((ext_vector_type(8)));
typedef _Float16 half4 __attribute__((ext_vector_type(4)));
typedef float floatx4 __attribute__((ext_vector_type(4)));

__device__ __forceinline__ floatx4 mfma16(half8 a, half8 b, floatx4 c) {
    return __builtin_amdgcn_mfma_f32_16x16x32_f16(a, b, c, 0, 0, 0);
}

// ---------------------------------------------------------------------------
// Kernel 1: projection GEMM.  C[m,e] = sum_d X[m,d] * W[e,d] + bias[e]
// X: [32768,512] fp32, W: [512,512] fp32 (row-major [e][d]).
// vmode==0: write fp16 out[m][e] (row-major [32768][512])
// vmode==1: write fp16 transposed per batch: out[b][e][s]  (V^T for PV)
// ---------------------------------------------------------------------------
__global__ __launch_bounds__(256) void proj_kernel(
    const float* __restrict__ X, const float* __restrict__ W,
    const float* __restrict__ bias, _Float16* __restrict__ out, int vmode)
{
    __shared__ _Float16 Ah[128][40];
    __shared__ _Float16 Bh[128][40];
    const int t = threadIdx.x;
    const int l = t & 63;
    const int wv = t >> 6;
    const int wrO = (wv >> 1) * 64;
    const int wcO = (wv & 1) * 64;
    const int fr = l & 15;
    const int fk = (l >> 4) * 8;
    const int mBase = blockIdx.y * 128;
    const int eBase = blockIdx.x * 128;

    floatx4 acc[4][4] = {};

    for (int kk = 0; kk < D_; kk += 32) {
        __syncthreads();
        // stage X tile [128][32] fp32 -> fp16
        #pragma unroll
        for (int i = 0; i < 4; ++i) {
            int f = t + i * 256;
            int r = f >> 3, c = f & 7;
            float4 v = *(const float4*)&X[(size_t)(mBase + r) * D_ + kk + c * 4];
            half4 h = { (_Float16)v.x, (_Float16)v.y, (_Float16)v.z, (_Float16)v.w };
            *(half4*)&Ah[r][c * 4] = h;
        }
        // stage W tile [128][32] fp32 -> fp16
        #pragma unroll
        for (int i = 0; i < 4; ++i) {
            int f = t + i * 256;
            int r = f >> 3, c = f & 7;
            float4 v = *(const float4*)&W[(size_t)(eBase + r) * D_ + kk + c * 4];
            half4 h = { (_Float16)v.x, (_Float16)v.y, (_Float16)v.z, (_Float16)v.w };
            *(half4*)&Bh[r][c * 4] = h;
        }
        __syncthreads();
        half8 af[4], bf[4];
        #pragma unroll
        for (int mi = 0; mi < 4; ++mi) af[mi] = *(half8*)&Ah[wrO + mi * 16 + fr][fk];
        #pragma unroll
        for (int ni = 0; ni < 4; ++ni) bf[ni] = *(half8*)&Bh[wcO + ni * 16 + fr][fk];
        #pragma unroll
        for (int mi = 0; mi < 4; ++mi)
            #pragma unroll
            for (int ni = 0; ni < 4; ++ni)
                acc[mi][ni] = mfma16(af[mi], bf[ni], acc[mi][ni]);
    }

    #pragma unroll
    for (int mi = 0; mi < 4; ++mi) {
        #pragma unroll
        for (int ni = 0; ni < 4; ++ni) {
            const int col  = eBase + wcO + ni * 16 + fr;
            const int row0 = mBase + wrO + mi * 16 + (l >> 4) * 4;
            const float bv = bias[col];
            if (vmode == 0) {
                #pragma unroll
                for (int j = 0; j < 4; ++j)
                    out[(size_t)(row0 + j) * D_ + col] = (_Float16)(acc[mi][ni][j] + bv);
            } else {
                const int b = row0 >> 11;
                const int s = row0 & (S_ - 1);
                half4 h;
                #pragma unroll
                for (int j = 0; j < 4; ++j) h[j] = (_Float16)(acc[mi][ni][j] + bv);
                *(half4*)&out[((size_t)b * D_ + col) * S_ + s] = h;
            }
        }
    }
}

// ---------------------------------------------------------------------------
// Kernel 2: scores.  weights[b][q][k] = scale * sum_d Q[b,q,d] K[b,k,d]
// Swapped operands: A = K tile (rows=k), B = Q tile (cols=q) so the 4 acc
// regs per lane are k-contiguous -> float4 stores.
// ---------------------------------------------------------------------------
__global__ __launch_bounds__(256) void scores_kernel(
    const _Float16* __restrict__ Qh, const _Float16* __restrict__ Kh,
    float* __restrict__ Wout)
{
    __shared__ _Float16 Ah[128][40];  // K tile
    __shared__ _Float16 Bh[128][40];  // Q tile
    const int t = threadIdx.x;
    const int l = t & 63;
    const int wv = t >> 6;
    const int wrO = (wv >> 1) * 64;
    const int wcO = (wv & 1) * 64;
    const int fr = l & 15;
    const int fk = (l >> 4) * 8;
    const int b = blockIdx.z;
    const int kBase = blockIdx.y * 128;
    const int qBase = blockIdx.x * 128;
    const _Float16* Kb = Kh + (size_t)b * S_ * D_;
    const _Float16* Qb = Qh + (size_t)b * S_ * D_;

    floatx4 acc[4][4] = {};

    for (int kk = 0; kk < D_; kk += 32) {
        __syncthreads();
        #pragma unroll
        for (int i = 0; i < 2; ++i) {
            int f = t + i * 256;
            int r = f >> 2, c = f & 3;
            *(uint4*)&Ah[r][c * 8] = *(const uint4*)&Kb[(size_t)(kBase + r) * D_ + kk + c * 8];
            *(uint4*)&Bh[r][c * 8] = *(const uint4*)&Qb[(size_t)(qBase + r) * D_ + kk + c * 8];
        }
        __syncthreads();
        half8 af[4], bf[4];
        #pragma unroll
        for (int mi = 0; mi < 4; ++mi) af[mi] = *(half8*)&Ah[wrO + mi * 16 + fr][fk];
        #pragma unroll
        for (int ni = 0; ni < 4; ++ni) bf[ni] = *(half8*)&Bh[wcO + ni * 16 + fr][fk];
        #pragma unroll
        for (int mi = 0; mi < 4; ++mi)
            #pragma unroll
            for (int ni = 0; ni < 4; ++ni)
                acc[mi][ni] = mfma16(af[mi], bf[ni], acc[mi][ni]);
    }

    const float scale = 0.044194173824159216f;  // 1/sqrt(512)
    #pragma unroll
    for (int mi = 0; mi < 4; ++mi) {
        #pragma unroll
        for (int ni = 0; ni < 4; ++ni) {
            const int krow0 = kBase + wrO + mi * 16 + (l >> 4) * 4;
            const int qcol  = qBase + wcO + ni * 16 + fr;
            float4 v;
            v.x = acc[mi][ni][0] * scale;
            v.y = acc[mi][ni][1] * scale;
            v.z = acc[mi][ni][2] * scale;
            v.w = acc[mi][ni][3] * scale;
            *(float4*)&Wout[((size_t)b * S_ + qcol) * S_ + krow0] = v;
        }
    }
}

// ---------------------------------------------------------------------------
// Kernel 3: row softmax in place over 2048 cols. One block per row.
// ---------------------------------------------------------------------------
__global__ __launch_bounds__(256) void softmax_kernel(float* __restrict__ Wt)
{
    __shared__ float red[4];
    float* p = Wt + (size_t)blockIdx.x * S_;
    const int t = threadIdx.x;
    const int l = t & 63;
    const int wv = t >> 6;

    float4 v0 = ((float4*)p)[t];
    float4 v1 = ((float4*)p)[t + 256];

    float m = fmaxf(fmaxf(fmaxf(v0.x, v0.y), fmaxf(v0.z, v0.w)),
                    fmaxf(fmaxf(v1.x, v1.y), fmaxf(v1.z, v1.w)));
    #pragma unroll
    for (int off = 32; off > 0; off >>= 1) m = fmaxf(m, __shfl_xor(m, off));
    if (l == 0) red[wv] = m;
    __syncthreads();
    m = fmaxf(fmaxf(red[0], red[1]), fmaxf(red[2], red[3]));
    __syncthreads();

    v0.x = __expf(v0.x - m); v0.y = __expf(v0.y - m);
    v0.z = __expf(v0.z - m); v0.w = __expf(v0.w - m);
    v1.x = __expf(v1.x - m); v1.y = __expf(v1.y - m);
    v1.z = __expf(v1.z - m); v1.w = __expf(v1.w - m);

    float s = v0.x + v0.y + v0.z + v0.w + v1.x + v1.y + v1.z + v1.w;
    #pragma unroll
    for (int off = 32; off > 0; off >>= 1) s += __shfl_xor(s, off);
    if (l == 0) red[wv] = s;
    __syncthreads();
    s = red[0] + red[1] + red[2] + red[3];
    const float inv = 1.0f / s;

    v0.x *= inv; v0.y *= inv; v0.z *= inv; v0.w *= inv;
    v1.x *= inv; v1.y *= inv; v1.z *= inv; v1.w *= inv;
    ((float4*)p)[t] = v0;
    ((float4*)p)[t + 256] = v1;
}

// ---------------------------------------------------------------------------
// Kernel 4: PV.  out[b][q][d] = sum_k weights[b,q,k] * V[b,k,d]
// A = V^T tile (rows=d, contiguous k), B = weights tile (rows=q, fp32->fp16).
// acc regs per lane are d-contiguous -> float4 stores.
// ---------------------------------------------------------------------------
__global__ __launch_bounds__(256) void pv_kernel(
    const float* __restrict__ Wt, const _Float16* __restrict__ Vt,
    float* __restrict__ Out)
{
    __shared__ _Float16 Ah[128][40];  // Vt tile
    __shared__ _Float16 Bh[128][40];  // weights tile
    const int t = threadIdx.x;
    const int l = t & 63;
    const int wv = t >> 6;
    const int wrO = (wv >> 1) * 64;
    const int wcO = (wv & 1) * 64;
    const int fr = l & 15;
    const int fk = (l >> 4) * 8;
    const int b = blockIdx.z;
    const int dBase = blockIdx.y * 128;
    const int qBase = blockIdx.x * 128;
    const _Float16* Vb = Vt + (size_t)b * D_ * S_;
    const float* Wb = Wt + (size_t)b * S_ * S_;

    floatx4 acc[4][4] = {};

    for (int kk = 0; kk < S_; kk += 32) {
        __syncthreads();
        #pragma unroll
        for (int i = 0; i < 2; ++i) {
            int f = t + i * 256;
            int r = f >> 2, c = f & 3;
            *(uint4*)&Ah[r][c * 8] = *(const uint4*)&Vb[(size_t)(dBase + r) * S_ + kk + c * 8];
        }
        #pragma unroll
        for (int i = 0; i < 4; ++i) {
            int f = t + i * 256;
            int r = f >> 3, c = f & 7;
            float4 v = *(const float4*)&Wb[(size_t)(qBase + r) * S_ + kk + c * 4];
            half4 h = { (_Float16)v.x, (_Float16)v.y, (_Float16)v.z, (_Float16)v.w };
            *(half4*)&Bh[r][c * 4] = h;
        }
        __syncthreads();
        half8 af[4], bf[4];
        #pragma unroll
        for (int mi = 0; mi < 4; ++mi) af[mi] = *(half8*)&Ah[wrO + mi * 16 + fr][fk];
        #pragma unroll
        for (int ni = 0; ni < 4; ++ni) bf[ni] = *(half8*)&Bh[wcO + ni * 16 + fr][fk];
        #pragma unroll
        for (int mi = 0; mi < 4; ++mi)
            #pragma unroll
            for (int ni = 0; ni < 4; ++ni)
                acc[mi][ni] = mfma16(af[mi], bf[ni], acc[mi][ni]);
    }

    #pragma unroll
    for (int mi = 0; mi < 4; ++mi) {
        #pragma unroll
        for (int ni = 0; ni < 4; ++ni) {
            const int d0 = dBase + wrO + mi * 16 + (l >> 4) * 4;
            const int q  = qBase + wcO + ni * 16 + fr;
            float4 v;
            v.x = acc[mi][ni][0];
            v.y = acc[mi][ni][1];
            v.z = acc[mi][ni][2];
            v.w = acc[mi][ni][3];
            *(float4*)&Out[((size_t)b * S_ + q) * D_ + d0] = v;
        }
    }
}

// ---------------------------------------------------------------------------
extern "C" void kernel_launch(void* const* d_in, const int* in_sizes, int n_in,
                              void* d_out, int out_size, void* d_ws, size_t ws_size,
                              hipStream_t stream)
{
    const float* x  = (const float*)d_in[0];
    const float* Wq = (const float*)d_in[1];
    const float* bq = (const float*)d_in[2];
    const float* Wk = (const float*)d_in[3];
    const float* bk = (const float*)d_in[4];
    const float* Wv = (const float*)d_in[5];
    const float* bv = (const float*)d_in[6];

    float* out = (float*)d_out;                       // [16,2048,512]
    float* wts = out + (size_t)B_ * S_ * D_;          // [16,2048,2048]

    _Float16* Qh = (_Float16*)d_ws;                   // [32768][512]
    _Float16* Kh = Qh + (size_t)MTOT * D_;            // [32768][512]
    _Float16* Vt = Kh + (size_t)MTOT * D_;            // [16][512][2048]

    dim3 blk(256);
    proj_kernel<<<dim3(D_ / 128, MTOT / 128), blk, 0, stream>>>(x, Wq, bq, Qh, 0);
    proj_kernel<<<dim3(D_ / 128, MTOT / 128), blk, 0, stream>>>(x, Wk, bk, Kh, 0);
    proj_kernel<<<dim3(D_ / 128, MTOT / 128), blk, 0, stream>>>(x, Wv, bv, Vt, 1);
    scores_kernel<<<dim3(S_ / 128, S_ / 128, B_), blk, 0, stream>>>(Qh, Kh, wts);
    softmax_kernel<<<dim3(B_ * S_), blk, 0, stream>>>(wts);
    pv_kernel<<<dim3(S_ / 128, D_ / 128, B_), blk, 0, stream>>>(wts, Vt, out);
}

// Round 3
// 511.944 us; speedup vs baseline: 1.1517x; 1.1517x over previous
//
#include <hip/hip_runtime.h>

#define B_ 16
#define S_ 2048
#define D_ 512
#define MTOT (B_ * S_)

typedef _Float16 half8 __attribute__((ext_vector_type(8)));
typedef _Float16 half4 __attribute__((ext_vector_type(4)));
typedef float floatx4 __attribute__((ext_vector_type(4)));

__device__ __forceinline__ floatx4 mfma16(half8 a, half8 b, floatx4 c) {
    return __builtin_amdgcn_mfma_f32_16x16x32_f16(a, b, c, 0, 0, 0);
}

// async global->LDS, 16B per lane. Per-wave LDS dest must be uniform base + lane*16.
__device__ __forceinline__ void gload16(const void* g, void* l) {
    __builtin_amdgcn_global_load_lds(
        (const __attribute__((address_space(1))) void*)g,
        (__attribute__((address_space(3))) void*)l, 16, 0, 0);
}

// ---------------------------------------------------------------------------
// Kernel 1: the three projection GEMMs, one launch (grid.z selects Q/K/V).
// C[m,e] = sum_d X[m,d] * W[e,d] + bias[e]
// z==0 -> Qh[m][e], z==1 -> Kh[m][e], z==2 -> Vt[b][e][s] (transposed)
// ---------------------------------------------------------------------------
__global__ __launch_bounds__(256) void proj_kernel(
    const float* __restrict__ X,
    const float* __restrict__ Wq, const float* __restrict__ bq,
    const float* __restrict__ Wk, const float* __restrict__ bk,
    const float* __restrict__ Wv, const float* __restrict__ bv,
    _Float16* __restrict__ Qh, _Float16* __restrict__ Kh,
    _Float16* __restrict__ Vt)
{
    const int z = blockIdx.z;
    const float* W; const float* bias; _Float16* out; int vmode;
    if (z == 0)      { W = Wq; bias = bq; out = Qh; vmode = 0; }
    else if (z == 1) { W = Wk; bias = bk; out = Kh; vmode = 0; }
    else             { W = Wv; bias = bv; out = Vt; vmode = 1; }

    __shared__ _Float16 Ah[128][40];
    __shared__ _Float16 Bh[128][40];
    const int t = threadIdx.x;
    const int l = t & 63;
    const int wv = t >> 6;
    const int wrO = (wv >> 1) * 64;
    const int wcO = (wv & 1) * 64;
    const int fr = l & 15;
    const int fk = (l >> 4) * 8;
    const int mBase = blockIdx.y * 128;
    const int eBase = blockIdx.x * 128;

    floatx4 acc[4][4] = {};

    for (int kk = 0; kk < D_; kk += 32) {
        __syncthreads();
        #pragma unroll
        for (int i = 0; i < 4; ++i) {
            int f = t + i * 256;
            int r = f >> 3, c = f & 7;
            float4 v = *(const float4*)&X[(size_t)(mBase + r) * D_ + kk + c * 4];
            half4 h = { (_Float16)v.x, (_Float16)v.y, (_Float16)v.z, (_Float16)v.w };
            *(half4*)&Ah[r][c * 4] = h;
        }
        #pragma unroll
        for (int i = 0; i < 4; ++i) {
            int f = t + i * 256;
            int r = f >> 3, c = f & 7;
            float4 v = *(const float4*)&W[(size_t)(eBase + r) * D_ + kk + c * 4];
            half4 h = { (_Float16)v.x, (_Float16)v.y, (_Float16)v.z, (_Float16)v.w };
            *(half4*)&Bh[r][c * 4] = h;
        }
        __syncthreads();
        half8 af[4], bf[4];
        #pragma unroll
        for (int mi = 0; mi < 4; ++mi) af[mi] = *(half8*)&Ah[wrO + mi * 16 + fr][fk];
        #pragma unroll
        for (int ni = 0; ni < 4; ++ni) bf[ni] = *(half8*)&Bh[wcO + ni * 16 + fr][fk];
        #pragma unroll
        for (int mi = 0; mi < 4; ++mi)
            #pragma unroll
            for (int ni = 0; ni < 4; ++ni)
                acc[mi][ni] = mfma16(af[mi], bf[ni], acc[mi][ni]);
    }

    #pragma unroll
    for (int mi = 0; mi < 4; ++mi) {
        #pragma unroll
        for (int ni = 0; ni < 4; ++ni) {
            const int col  = eBase + wcO + ni * 16 + fr;
            const int row0 = mBase + wrO + mi * 16 + (l >> 4) * 4;
            const float bv_ = bias[col];
            if (vmode == 0) {
                #pragma unroll
                for (int j = 0; j < 4; ++j)
                    out[(size_t)(row0 + j) * D_ + col] = (_Float16)(acc[mi][ni][j] + bv_);
            } else {
                const int b = row0 >> 11;
                const int s = row0 & (S_ - 1);
                half4 h;
                #pragma unroll
                for (int j = 0; j < 4; ++j) h[j] = (_Float16)(acc[mi][ni][j] + bv_);
                *(half4*)&out[((size_t)b * D_ + col) * S_ + s] = h;
            }
        }
    }
}

// ---------------------------------------------------------------------------
// Kernel 2: raw scores.  wts[b][q][k] = scale * sum_d Q[b,q,d] K[b,k,d]
// A = K tile, B = Q tile (acc k-contiguous -> float4 stores).
// fp16 tiles staged via global_load_lds into linear (unpadded) LDS.
// ---------------------------------------------------------------------------
__global__ __launch_bounds__(256) void scores_kernel(
    const _Float16* __restrict__ Qh, const _Float16* __restrict__ Kh,
    float* __restrict__ Wout)
{
    __shared__ _Float16 Ah[128 * 32];  // K tile, linear
    __shared__ _Float16 Bh[128 * 32];  // Q tile, linear
    const int t = threadIdx.x;
    const int l = t & 63;
    const int wv = t >> 6;
    const int wrO = (wv >> 1) * 64;
    const int wcO = (wv & 1) * 64;
    const int fr = l & 15;
    const int fk = (l >> 4) * 8;
    const int b = blockIdx.z;
    const int kBase = blockIdx.y * 128;
    const int qBase = blockIdx.x * 128;
    const _Float16* Kb = Kh + (size_t)b * S_ * D_;
    const _Float16* Qb = Qh + (size_t)b * S_ * D_;

    const int f0 = t, f1 = t + 256;          // 16B-chunk ids (512 per tile)
    const int r0 = f0 >> 2, c0 = f0 & 3;     // row, col-chunk (8 halves)
    const int r1 = f1 >> 2, c1 = f1 & 3;

    floatx4 acc[4][4] = {};

    for (int kk = 0; kk < D_; kk += 32) {
        __syncthreads();
        gload16(&Kb[(size_t)(kBase + r0) * D_ + kk + c0 * 8], (char*)Ah + f0 * 16);
        gload16(&Kb[(size_t)(kBase + r1) * D_ + kk + c1 * 8], (char*)Ah + f1 * 16);
        gload16(&Qb[(size_t)(qBase + r0) * D_ + kk + c0 * 8], (char*)Bh + f0 * 16);
        gload16(&Qb[(size_t)(qBase + r1) * D_ + kk + c1 * 8], (char*)Bh + f1 * 16);
        __syncthreads();
        half8 af[4], bf[4];
        #pragma unroll
        for (int mi = 0; mi < 4; ++mi) af[mi] = *(half8*)&Ah[(wrO + mi * 16 + fr) * 32 + fk];
        #pragma unroll
        for (int ni = 0; ni < 4; ++ni) bf[ni] = *(half8*)&Bh[(wcO + ni * 16 + fr) * 32 + fk];
        #pragma unroll
        for (int mi = 0; mi < 4; ++mi)
            #pragma unroll
            for (int ni = 0; ni < 4; ++ni)
                acc[mi][ni] = mfma16(af[mi], bf[ni], acc[mi][ni]);
    }

    const float scale = 0.044194173824159216f;  // 1/sqrt(512)
    #pragma unroll
    for (int mi = 0; mi < 4; ++mi) {
        #pragma unroll
        for (int ni = 0; ni < 4; ++ni) {
            const int krow0 = kBase + wrO + mi * 16 + (l >> 4) * 4;
            const int qcol  = qBase + wcO + ni * 16 + fr;
            float4 v;
            v.x = acc[mi][ni][0] * scale;
            v.y = acc[mi][ni][1] * scale;
            v.z = acc[mi][ni][2] * scale;
            v.w = acc[mi][ni][3] * scale;
            *(float4*)&Wout[((size_t)b * S_ + qcol) * S_ + krow0] = v;
        }
    }
}

// ---------------------------------------------------------------------------
// Kernel 3: fused softmax + PV.  One 1024-thread block owns a 128-q-row panel.
// Phase A: online max/sumexp per row from raw scores (in d_out).
// Phase B: k-loop; stage weights with exp(s-m)*inv applied (fp32 write-back
// in place -> final weights output) + V^T tile via global_load_lds; MFMA.
// out[b][q][d] = sum_k w[b,q,k] * V[b,k,d]
// ---------------------------------------------------------------------------
__global__ __launch_bounds__(1024) void pv_fused(
    float* __restrict__ Wt, const _Float16* __restrict__ Vt,
    float* __restrict__ Out)
{
    __shared__ _Float16 Vh[512 * 32];   // V^T tile [512 d][32 k], linear chunks
    __shared__ _Float16 Wh[128][40];    // weights tile [128 q][32 k], padded
    __shared__ float mRow[128];
    __shared__ float invRow[128];

    const int t = threadIdx.x;
    const int l = t & 63;
    const int wv = t >> 6;               // 0..15
    const int b = blockIdx.y;
    const int qBase = blockIdx.x * 128;
    float* Wb = Wt + ((size_t)b * S_ + qBase) * S_;      // [128][2048] panel
    const _Float16* Vb = Vt + (size_t)b * D_ * S_;

    // ---- Phase A: per-row max & inv-sum (wave wv owns rows wv*8 .. wv*8+7)
    for (int i = 0; i < 8; ++i) {
        const int r = wv * 8 + i;
        const float* row = Wb + (size_t)r * S_;
        float m = -1e30f, s = 0.f;
        #pragma unroll
        for (int ch = 0; ch < 8; ++ch) {
            float4 v = *(const float4*)&row[ch * 256 + l * 4];
            float lm = fmaxf(fmaxf(v.x, v.y), fmaxf(v.z, v.w));
            float M = fmaxf(m, lm);
            s = s * __expf(m - M)
              + __expf(v.x - M) + __expf(v.y - M) + __expf(v.z - M) + __expf(v.w - M);
            m = M;
        }
        #pragma unroll
        for (int off = 32; off > 0; off >>= 1) {
            float m2 = __shfl_xor(m, off);
            float s2 = __shfl_xor(s, off);
            float M = fmaxf(m, m2);
            s = s * __expf(m - M) + s2 * __expf(m2 - M);
            m = M;
        }
        if (l == 0) { mRow[r] = m; invRow[r] = 1.0f / s; }
    }
    __syncthreads();

    // ---- Phase B: GEMM with fused normalize
    // wave tile: 8 d-waves x 2 q-waves, each 64d x 64q
    const int dO = (wv >> 1) * 64;       // 0..448
    const int qO = (wv & 1) * 64;
    const int fr = l & 15;
    const int fk = (l >> 4) * 8;
    // weight staging assignment: thread t -> row rW, 4-float chunk cW
    const int rW = t >> 3;               // 0..127
    const int cW = (t & 7) * 4;          // 0..28
    const float mS  = mRow[rW];
    const float inS = invRow[rW];

    // V-tile chunk ids for this thread: g0 = t, g1 = t + 1024 (2048 chunks total)
    const int g0 = t, g1 = t + 1024;
    const int vr0 = g0 >> 2, vc0 = g0 & 3;
    const int vr1 = g1 >> 2, vc1 = g1 & 3;

    floatx4 acc[4][4] = {};

    for (int kk = 0; kk < S_; kk += 32) {
        __syncthreads();
        // V^T tile: 512 rows x 32 halves = 2048 chunks of 16B, two per thread.
        // LDS chunk g holds global (row g>>2, halves [(g&3)*8, (g&3)*8+8)).
        gload16(&Vb[(size_t)vr0 * S_ + kk + vc0 * 8], (char*)Vh + (size_t)g0 * 16);
        gload16(&Vb[(size_t)vr1 * S_ + kk + vc1 * 8], (char*)Vh + (size_t)g1 * 16);
        // weights tile: read raw, normalize, write back (final output), cvt fp16
        {
            float4 v = *(const float4*)&Wb[(size_t)rW * S_ + kk + cW];
            float4 w;
            w.x = __expf(v.x - mS) * inS;
            w.y = __expf(v.y - mS) * inS;
            w.z = __expf(v.z - mS) * inS;
            w.w = __expf(v.w - mS) * inS;
            *(float4*)&Wb[(size_t)rW * S_ + kk + cW] = w;
            half4 h = { (_Float16)w.x, (_Float16)w.y, (_Float16)w.z, (_Float16)w.w };
            *(half4*)&Wh[rW][cW] = h;
        }
        __syncthreads();
        half8 af[4], bf[4];
        #pragma unroll
        for (int mi = 0; mi < 4; ++mi) af[mi] = *(half8*)&Vh[(dO + mi * 16 + fr) * 32 + fk];
        #pragma unroll
        for (int ni = 0; ni < 4; ++ni) bf[ni] = *(half8*)&Wh[qO + ni * 16 + fr][fk];
        #pragma unroll
        for (int mi = 0; mi < 4; ++mi)
            #pragma unroll
            for (int ni = 0; ni < 4; ++ni)
                acc[mi][ni] = mfma16(af[mi], bf[ni], acc[mi][ni]);
    }

    #pragma unroll
    for (int mi = 0; mi < 4; ++mi) {
        #pragma unroll
        for (int ni = 0; ni < 4; ++ni) {
            const int d0 = dO + mi * 16 + (l >> 4) * 4;
            const int q  = qBase + qO + ni * 16 + fr;
            float4 v;
            v.x = acc[mi][ni][0];
            v.y = acc[mi][ni][1];
            v.z = acc[mi][ni][2];
            v.w = acc[mi][ni][3];
            *(float4*)&Out[((size_t)b * S_ + q) * D_ + d0] = v;
        }
    }
}

// ---------------------------------------------------------------------------
extern "C" void kernel_launch(void* const* d_in, const int* in_sizes, int n_in,
                              void* d_out, int out_size, void* d_ws, size_t ws_size,
                              hipStream_t stream)
{
    const float* x  = (const float*)d_in[0];
    const float* Wq = (const float*)d_in[1];
    const float* bq = (const float*)d_in[2];
    const float* Wk = (const float*)d_in[3];
    const float* bk = (const float*)d_in[4];
    const float* Wv = (const float*)d_in[5];
    const float* bv = (const float*)d_in[6];

    float* out = (float*)d_out;                       // [16,2048,512]
    float* wts = out + (size_t)B_ * S_ * D_;          // [16,2048,2048]

    _Float16* Qh = (_Float16*)d_ws;                   // [32768][512]
    _Float16* Kh = Qh + (size_t)MTOT * D_;            // [32768][512]
    _Float16* Vt = Kh + (size_t)MTOT * D_;            // [16][512][2048]

    proj_kernel<<<dim3(D_ / 128, MTOT / 128, 3), 256, 0, stream>>>(
        x, Wq, bq, Wk, bk, Wv, bv, Qh, Kh, Vt);
    scores_kernel<<<dim3(S_ / 128, S_ / 128, B_), 256, 0, stream>>>(Qh, Kh, wts);
    pv_fused<<<dim3(S_ / 128, B_), 1024, 0, stream>>>(wts, Vt, out);
}

// Round 4
// 494.680 us; speedup vs baseline: 1.1919x; 1.0349x over previous
//
#include <hip/hip_runtime.h>

#define B_ 16
#define S_ 2048
#define D_ 512
#define MTOT (B_ * S_)

typedef _Float16 half8 __attribute__((ext_vector_type(8)));
typedef _Float16 half4 __attribute__((ext_vector_type(4)));
typedef float floatx4 __attribute__((ext_vector_type(4)));

__device__ __forceinline__ floatx4 mfma16(half8 a, half8 b, floatx4 c) {
    return __builtin_amdgcn_mfma_f32_16x16x32_f16(a, b, c, 0, 0, 0);
}

// async global->LDS, 16B per lane. Per-wave LDS dest must be uniform base + lane*16.
__device__ __forceinline__ void gload16(const void* g, void* l) {
    __builtin_amdgcn_global_load_lds(
        (const __attribute__((address_space(1))) void*)g,
        (__attribute__((address_space(3))) void*)l, 16, 0, 0);
}

// ---------------------------------------------------------------------------
// Kernel 1: the three projection GEMMs, one launch (grid.z selects Q/K/V).
// ---------------------------------------------------------------------------
__global__ __launch_bounds__(256) void proj_kernel(
    const float* __restrict__ X,
    const float* __restrict__ Wq, const float* __restrict__ bq,
    const float* __restrict__ Wk, const float* __restrict__ bk,
    const float* __restrict__ Wv, const float* __restrict__ bv,
    _Float16* __restrict__ Qh, _Float16* __restrict__ Kh,
    _Float16* __restrict__ Vt)
{
    const int z = blockIdx.z;
    const float* W; const float* bias; _Float16* out; int vmode;
    if (z == 0)      { W = Wq; bias = bq; out = Qh; vmode = 0; }
    else if (z == 1) { W = Wk; bias = bk; out = Kh; vmode = 0; }
    else             { W = Wv; bias = bv; out = Vt; vmode = 1; }

    __shared__ _Float16 Ah[128][40];
    __shared__ _Float16 Bh[128][40];
    const int t = threadIdx.x;
    const int l = t & 63;
    const int wv = t >> 6;
    const int wrO = (wv >> 1) * 64;
    const int wcO = (wv & 1) * 64;
    const int fr = l & 15;
    const int fk = (l >> 4) * 8;
    const int mBase = blockIdx.y * 128;
    const int eBase = blockIdx.x * 128;

    floatx4 acc[4][4] = {};

    for (int kk = 0; kk < D_; kk += 32) {
        __syncthreads();
        #pragma unroll
        for (int i = 0; i < 4; ++i) {
            int f = t + i * 256;
            int r = f >> 3, c = f & 7;
            float4 v = *(const float4*)&X[(size_t)(mBase + r) * D_ + kk + c * 4];
            half4 h = { (_Float16)v.x, (_Float16)v.y, (_Float16)v.z, (_Float16)v.w };
            *(half4*)&Ah[r][c * 4] = h;
        }
        #pragma unroll
        for (int i = 0; i < 4; ++i) {
            int f = t + i * 256;
            int r = f >> 3, c = f & 7;
            float4 v = *(const float4*)&W[(size_t)(eBase + r) * D_ + kk + c * 4];
            half4 h = { (_Float16)v.x, (_Float16)v.y, (_Float16)v.z, (_Float16)v.w };
            *(half4*)&Bh[r][c * 4] = h;
        }
        __syncthreads();
        half8 af[4], bf[4];
        #pragma unroll
        for (int mi = 0; mi < 4; ++mi) af[mi] = *(half8*)&Ah[wrO + mi * 16 + fr][fk];
        #pragma unroll
        for (int ni = 0; ni < 4; ++ni) bf[ni] = *(half8*)&Bh[wcO + ni * 16 + fr][fk];
        #pragma unroll
        for (int mi = 0; mi < 4; ++mi)
            #pragma unroll
            for (int ni = 0; ni < 4; ++ni)
                acc[mi][ni] = mfma16(af[mi], bf[ni], acc[mi][ni]);
    }

    #pragma unroll
    for (int mi = 0; mi < 4; ++mi) {
        #pragma unroll
        for (int ni = 0; ni < 4; ++ni) {
            const int col  = eBase + wcO + ni * 16 + fr;
            const int row0 = mBase + wrO + mi * 16 + (l >> 4) * 4;
            const float bv_ = bias[col];
            if (vmode == 0) {
                #pragma unroll
                for (int j = 0; j < 4; ++j)
                    out[(size_t)(row0 + j) * D_ + col] = (_Float16)(acc[mi][ni][j] + bv_);
            } else {
                const int b = row0 >> 11;
                const int s = row0 & (S_ - 1);
                half4 h;
                #pragma unroll
                for (int j = 0; j < 4; ++j) h[j] = (_Float16)(acc[mi][ni][j] + bv_);
                *(half4*)&out[((size_t)b * D_ + col) * S_ + s] = h;
            }
        }
    }
}

// ---------------------------------------------------------------------------
// Kernel 2: scores + per-block softmax partials.
// Writes e = exp(S*scale - m_blk) (fp32) into wts, and per-(kblk,q) stats
// {m_blk, s_blk} into the stats array.  A = K tile, B = Q tile (swapped),
// both staged via gload16 with XOR-swizzled source chunks.
// ---------------------------------------------------------------------------
__global__ __launch_bounds__(256) void scores_kernel(
    const _Float16* __restrict__ Qh, const _Float16* __restrict__ Kh,
    float* __restrict__ Wout, float2* __restrict__ stats)
{
    __shared__ _Float16 Ah[128 * 32];  // K tile, linear chunks (src-swizzled)
    __shared__ _Float16 Bh[128 * 32];  // Q tile
    __shared__ float smR[4][64];       // cross-wave stat partials
    const int t = threadIdx.x;
    const int l = t & 63;
    const int wv = t >> 6;
    const int wrO = (wv >> 1) * 64;
    const int wcO = (wv & 1) * 64;
    const int fr = l & 15;
    const int fk = (l >> 4) * 8;
    const int b = blockIdx.z;
    const int kblk = blockIdx.y;
    const int kBase = kblk * 128;
    const int qBase = blockIdx.x * 128;
    const _Float16* Kb = Kh + (size_t)b * S_ * D_;
    const _Float16* Qb = Qh + (size_t)b * S_ * D_;

    // staging: LDS chunk f (row r=f>>2, slot c=f&3) holds global chunk c^((r>>1)&3)
    const int f0 = t, f1 = t + 256;
    const int r0 = f0 >> 2, c0 = (f0 & 3) ^ ((r0 >> 1) & 3);
    const int r1 = f1 >> 2, c1 = (f1 & 3) ^ ((r1 >> 1) & 3);

    floatx4 acc[4][4] = {};

    for (int kk = 0; kk < D_; kk += 32) {
        __syncthreads();
        gload16(&Kb[(size_t)(kBase + r0) * D_ + kk + c0 * 8], (char*)Ah + f0 * 16);
        gload16(&Kb[(size_t)(kBase + r1) * D_ + kk + c1 * 8], (char*)Ah + f1 * 16);
        gload16(&Qb[(size_t)(qBase + r0) * D_ + kk + c0 * 8], (char*)Bh + f0 * 16);
        gload16(&Qb[(size_t)(qBase + r1) * D_ + kk + c1 * 8], (char*)Bh + f1 * 16);
        __syncthreads();
        half8 af[4], bf[4];
        #pragma unroll
        for (int mi = 0; mi < 4; ++mi) {
            int row = wrO + mi * 16 + fr;
            int c = (fk >> 3) ^ ((row >> 1) & 3);
            af[mi] = *(half8*)&Ah[row * 32 + c * 8];
        }
        #pragma unroll
        for (int ni = 0; ni < 4; ++ni) {
            int row = wcO + ni * 16 + fr;
            int c = (fk >> 3) ^ ((row >> 1) & 3);
            bf[ni] = *(half8*)&Bh[row * 32 + c * 8];
        }
        #pragma unroll
        for (int mi = 0; mi < 4; ++mi)
            #pragma unroll
            for (int ni = 0; ni < 4; ++ni)
                acc[mi][ni] = mfma16(af[mi], bf[ni], acc[mi][ni]);
    }

    // ---- epilogue: scale, per-q block max over k, e = exp, block sum, stats.
    const float scale = 0.044194173824159216f;  // 1/sqrt(512)
    float pm[4];
    #pragma unroll
    for (int ni = 0; ni < 4; ++ni) {
        float m = -1e30f;
        #pragma unroll
        for (int mi = 0; mi < 4; ++mi)
            #pragma unroll
            for (int j = 0; j < 4; ++j) {
                acc[mi][ni][j] *= scale;
                m = fmaxf(m, acc[mi][ni][j]);
            }
        pm[ni] = m;
    }
    #pragma unroll
    for (int ni = 0; ni < 4; ++ni) {
        pm[ni] = fmaxf(pm[ni], __shfl_xor(pm[ni], 16));
        pm[ni] = fmaxf(pm[ni], __shfl_xor(pm[ni], 32));
    }
    if (l < 16) {
        #pragma unroll
        for (int ni = 0; ni < 4; ++ni) smR[wv][ni * 16 + l] = pm[ni];
    }
    __syncthreads();
    float mb[4], ps[4];
    #pragma unroll
    for (int ni = 0; ni < 4; ++ni)
        mb[ni] = fmaxf(smR[wv & 1][ni * 16 + fr], smR[(wv & 1) + 2][ni * 16 + fr]);
    #pragma unroll
    for (int ni = 0; ni < 4; ++ni) {
        float s = 0.f;
        #pragma unroll
        for (int mi = 0; mi < 4; ++mi)
            #pragma unroll
            for (int j = 0; j < 4; ++j) {
                float e = __expf(acc[mi][ni][j] - mb[ni]);
                acc[mi][ni][j] = e;
                s += e;
            }
        ps[ni] = s;
    }
    #pragma unroll
    for (int ni = 0; ni < 4; ++ni) {
        ps[ni] += __shfl_xor(ps[ni], 16);
        ps[ni] += __shfl_xor(ps[ni], 32);
    }
    __syncthreads();
    if (l < 16) {
        #pragma unroll
        for (int ni = 0; ni < 4; ++ni) smR[wv][ni * 16 + l] = ps[ni];
    }
    __syncthreads();
    if (wv < 2 && l < 16) {
        #pragma unroll
        for (int ni = 0; ni < 4; ++ni) {
            const int ql = wv * 64 + ni * 16 + l;
            float sb = smR[wv][ni * 16 + l] + smR[wv + 2][ni * 16 + l];
            float2 st; st.x = mb[ni]; st.y = sb;
            stats[(size_t)(b * 16 + kblk) * S_ + qBase + ql] = st;
        }
    }

    // ---- store e (fp32) to wts
    #pragma unroll
    for (int mi = 0; mi < 4; ++mi) {
        #pragma unroll
        for (int ni = 0; ni < 4; ++ni) {
            const int krow0 = kBase + wrO + mi * 16 + (l >> 4) * 4;
            const int qcol  = qBase + wcO + ni * 16 + fr;
            float4 v;
            v.x = acc[mi][ni][0];
            v.y = acc[mi][ni][1];
            v.z = acc[mi][ni][2];
            v.w = acc[mi][ni][3];
            *(float4*)&Wout[((size_t)b * S_ + qcol) * S_ + krow0] = v;
        }
    }
}

// ---------------------------------------------------------------------------
// Kernel 3: finalize weights + PV.  One 512-thread block owns a 64-q panel.
// Phase A: combine per-kblk stats -> scale[kblk][q] = exp(m_blk-m)/s.
// Phase B: k-loop: w = e * scale (write fp32 weights output), cvt fp16 -> LDS;
// V^T tile via swizzled gload16; MFMA.  e prefetched during MFMA phase.
// ---------------------------------------------------------------------------
__global__ __launch_bounds__(512) void pv2(
    float* __restrict__ Wt, const _Float16* __restrict__ Vt,
    const float2* __restrict__ stats, float* __restrict__ Out)
{
    __shared__ _Float16 Vh[512 * 32];   // V^T tile, linear chunks (src-swizzled)
    __shared__ _Float16 Wh[64][40];     // weights tile, padded
    __shared__ float smM[16][64];
    __shared__ float smS[16][64];
    __shared__ float smScale[16][64];

    const int t = threadIdx.x;
    const int l = t & 63;
    const int wv = t >> 6;               // 0..7 (d-group)
    const int b = blockIdx.y;
    const int qBase = blockIdx.x * 64;
    float* Wb = Wt + ((size_t)b * S_ + qBase) * S_;      // [64][2048] panel
    const _Float16* Vb = Vt + (size_t)b * D_ * S_;

    // ---- Phase A: stats combine
    for (int i = t; i < 1024; i += 512) {
        int kb = i >> 6, q = i & 63;
        float2 v = stats[(size_t)(b * 16 + kb) * S_ + qBase + q];
        smM[kb][q] = v.x; smS[kb][q] = v.y;
    }
    __syncthreads();
    if (t < 64) {
        float m = -1e30f;
        #pragma unroll
        for (int kb = 0; kb < 16; ++kb) m = fmaxf(m, smM[kb][t]);
        float s = 0.f;
        #pragma unroll
        for (int kb = 0; kb < 16; ++kb) s += smS[kb][t] * __expf(smM[kb][t] - m);
        const float inv = 1.0f / s;
        #pragma unroll
        for (int kb = 0; kb < 16; ++kb) smScale[kb][t] = __expf(smM[kb][t] - m) * inv;
    }
    __syncthreads();

    const int fr = l & 15;
    const int fk = (l >> 4) * 8;
    const int rW = t >> 3;               // 0..63 (q row for W staging)
    const int cW = (t & 7) * 4;          // float offset 0..28

    floatx4 acc[4][4] = {};
    float4 e_pf = *(const float4*)&Wb[(size_t)rW * S_ + cW];

    for (int kk = 0; kk < S_; kk += 32) {
        const float sc = smScale[kk >> 7][rW];
        __syncthreads();
        // V^T tile: 512 rows x 32 halves = 2048 chunks; 4 gload16/thread,
        // source chunk XOR-swizzled so reads are conflict-free.
        #pragma unroll
        for (int i = 0; i < 4; ++i) {
            int g = t + i * 512;
            int vr = g >> 2;
            int vs = (g & 3) ^ ((vr >> 1) & 3);
            gload16(&Vb[(size_t)vr * S_ + kk + vs * 8], (char*)Vh + (size_t)g * 16);
        }
        // W tile: w = e * scale; write fp32 weights output; fp16 to LDS
        {
            float4 w;
            w.x = e_pf.x * sc; w.y = e_pf.y * sc;
            w.z = e_pf.z * sc; w.w = e_pf.w * sc;
            *(float4*)&Wb[(size_t)rW * S_ + kk + cW] = w;
            half4 h = { (_Float16)w.x, (_Float16)w.y, (_Float16)w.z, (_Float16)w.w };
            *(half4*)&Wh[rW][cW] = h;
        }
        __syncthreads();
        if (kk + 32 < S_) e_pf = *(const float4*)&Wb[(size_t)rW * S_ + kk + 32 + cW];
        half8 af[4], bf[4];
        #pragma unroll
        for (int mi = 0; mi < 4; ++mi) {
            int row = wv * 64 + mi * 16 + fr;
            int c = (fk >> 3) ^ ((row >> 1) & 3);
            af[mi] = *(half8*)&Vh[row * 32 + c * 8];
        }
        #pragma unroll
        for (int ni = 0; ni < 4; ++ni) bf[ni] = *(half8*)&Wh[ni * 16 + fr][fk];
        #pragma unroll
        for (int mi = 0; mi < 4; ++mi)
            #pragma unroll
            for (int ni = 0; ni < 4; ++ni)
                acc[mi][ni] = mfma16(af[mi], bf[ni], acc[mi][ni]);
    }

    #pragma unroll
    for (int mi = 0; mi < 4; ++mi) {
        #pragma unroll
        for (int ni = 0; ni < 4; ++ni) {
            const int d0 = wv * 64 + mi * 16 + (l >> 4) * 4;
            const int q  = qBase + ni * 16 + fr;
            float4 v;
            v.x = acc[mi][ni][0];
            v.y = acc[mi][ni][1];
            v.z = acc[mi][ni][2];
            v.w = acc[mi][ni][3];
            *(float4*)&Out[((size_t)b * S_ + q) * D_ + d0] = v;
        }
    }
}

// ---------------------------------------------------------------------------
extern "C" void kernel_launch(void* const* d_in, const int* in_sizes, int n_in,
                              void* d_out, int out_size, void* d_ws, size_t ws_size,
                              hipStream_t stream)
{
    const float* x  = (const float*)d_in[0];
    const float* Wq = (const float*)d_in[1];
    const float* bq = (const float*)d_in[2];
    const float* Wk = (const float*)d_in[3];
    const float* bk = (const float*)d_in[4];
    const float* Wv = (const float*)d_in[5];
    const float* bv = (const float*)d_in[6];

    float* out = (float*)d_out;                       // [16,2048,512]
    float* wts = out + (size_t)B_ * S_ * D_;          // [16,2048,2048]

    _Float16* Qh = (_Float16*)d_ws;                   // 32 MB
    _Float16* Kh = Qh + (size_t)MTOT * D_;            // 32 MB
    _Float16* Vt = Kh + (size_t)MTOT * D_;            // 32 MB
    float2* stats = (float2*)(Vt + (size_t)MTOT * D_); // 4 MB: [b][kblk][q]{m,s}

    proj_kernel<<<dim3(D_ / 128, MTOT / 128, 3), 256, 0, stream>>>(
        x, Wq, bq, Wk, bk, Wv, bv, Qh, Kh, Vt);
    scores_kernel<<<dim3(S_ / 128, S_ / 128, B_), 256, 0, stream>>>(Qh, Kh, wts, stats);
    pv2<<<dim3(S_ / 64, B_), 512, 0, stream>>>(wts, Vt, stats, out);
}

// Round 5
// 472.786 us; speedup vs baseline: 1.2471x; 1.0463x over previous
//
#include <hip/hip_runtime.h>

#define B_ 16
#define S_ 2048
#define D_ 512
#define MTOT (B_ * S_)

typedef _Float16 half8 __attribute__((ext_vector_type(8)));
typedef _Float16 half4 __attribute__((ext_vector_type(4)));
typedef float floatx4 __attribute__((ext_vector_type(4)));

__device__ __forceinline__ floatx4 mfma16(half8 a, half8 b, floatx4 c) {
    return __builtin_amdgcn_mfma_f32_16x16x32_f16(a, b, c, 0, 0, 0);
}

// async global->LDS, 16B per lane. Per-wave LDS dest must be uniform base + lane*16.
__device__ __forceinline__ void gload16(const void* g, void* l) {
    __builtin_amdgcn_global_load_lds(
        (const __attribute__((address_space(1))) void*)g,
        (__attribute__((address_space(3))) void*)l, 16, 0, 0);
}

// ---------------------------------------------------------------------------
// Kernel 1: the three projection GEMMs, one launch (grid.z selects Q/K/V).
// ---------------------------------------------------------------------------
__global__ __launch_bounds__(256) void proj_kernel(
    const float* __restrict__ X,
    const float* __restrict__ Wq, const float* __restrict__ bq,
    const float* __restrict__ Wk, const float* __restrict__ bk,
    const float* __restrict__ Wv, const float* __restrict__ bv,
    _Float16* __restrict__ Qh, _Float16* __restrict__ Kh,
    _Float16* __restrict__ Vt)
{
    const int z = blockIdx.z;
    const float* W; const float* bias; _Float16* out; int vmode;
    if (z == 0)      { W = Wq; bias = bq; out = Qh; vmode = 0; }
    else if (z == 1) { W = Wk; bias = bk; out = Kh; vmode = 0; }
    else             { W = Wv; bias = bv; out = Vt; vmode = 1; }

    __shared__ _Float16 Ah[128][40];
    __shared__ _Float16 Bh[128][40];
    const int t = threadIdx.x;
    const int l = t & 63;
    const int wv = t >> 6;
    const int wrO = (wv >> 1) * 64;
    const int wcO = (wv & 1) * 64;
    const int fr = l & 15;
    const int fk = (l >> 4) * 8;
    const int mBase = blockIdx.y * 128;
    const int eBase = blockIdx.x * 128;

    floatx4 acc[4][4] = {};

    for (int kk = 0; kk < D_; kk += 32) {
        __syncthreads();
        #pragma unroll
        for (int i = 0; i < 4; ++i) {
            int f = t + i * 256;
            int r = f >> 3, c = f & 7;
            float4 v = *(const float4*)&X[(size_t)(mBase + r) * D_ + kk + c * 4];
            half4 h = { (_Float16)v.x, (_Float16)v.y, (_Float16)v.z, (_Float16)v.w };
            *(half4*)&Ah[r][c * 4] = h;
        }
        #pragma unroll
        for (int i = 0; i < 4; ++i) {
            int f = t + i * 256;
            int r = f >> 3, c = f & 7;
            float4 v = *(const float4*)&W[(size_t)(eBase + r) * D_ + kk + c * 4];
            half4 h = { (_Float16)v.x, (_Float16)v.y, (_Float16)v.z, (_Float16)v.w };
            *(half4*)&Bh[r][c * 4] = h;
        }
        __syncthreads();
        half8 af[4], bf[4];
        #pragma unroll
        for (int mi = 0; mi < 4; ++mi) af[mi] = *(half8*)&Ah[wrO + mi * 16 + fr][fk];
        #pragma unroll
        for (int ni = 0; ni < 4; ++ni) bf[ni] = *(half8*)&Bh[wcO + ni * 16 + fr][fk];
        #pragma unroll
        for (int mi = 0; mi < 4; ++mi)
            #pragma unroll
            for (int ni = 0; ni < 4; ++ni)
                acc[mi][ni] = mfma16(af[mi], bf[ni], acc[mi][ni]);
    }

    #pragma unroll
    for (int mi = 0; mi < 4; ++mi) {
        #pragma unroll
        for (int ni = 0; ni < 4; ++ni) {
            const int col  = eBase + wcO + ni * 16 + fr;
            const int row0 = mBase + wrO + mi * 16 + (l >> 4) * 4;
            const float bv_ = bias[col];
            if (vmode == 0) {
                #pragma unroll
                for (int j = 0; j < 4; ++j)
                    out[(size_t)(row0 + j) * D_ + col] = (_Float16)(acc[mi][ni][j] + bv_);
            } else {
                const int b = row0 >> 11;
                const int s = row0 & (S_ - 1);
                half4 h;
                #pragma unroll
                for (int j = 0; j < 4; ++j) h[j] = (_Float16)(acc[mi][ni][j] + bv_);
                *(half4*)&out[((size_t)b * D_ + col) * S_ + s] = h;
            }
        }
    }
}

// ---------------------------------------------------------------------------
// Kernel 2: scores + per-block softmax partials.
// Writes e = exp(S*scale - m_blk) as FP16 into the upper half of each q-row's
// 8KB slot in the weights output region (byte rowbase + 4096 + 2k), plus
// per-(kblk,q) stats {m_blk, s_blk}.
// ---------------------------------------------------------------------------
__global__ __launch_bounds__(256) void scores_kernel(
    const _Float16* __restrict__ Qh, const _Float16* __restrict__ Kh,
    float* __restrict__ Wout, float2* __restrict__ stats)
{
    __shared__ _Float16 Ah[128 * 32];  // K tile, linear chunks (src-swizzled)
    __shared__ _Float16 Bh[128 * 32];  // Q tile
    __shared__ float smR[4][64];       // cross-wave stat partials
    const int t = threadIdx.x;
    const int l = t & 63;
    const int wv = t >> 6;
    const int wrO = (wv >> 1) * 64;
    const int wcO = (wv & 1) * 64;
    const int fr = l & 15;
    const int fk = (l >> 4) * 8;
    const int b = blockIdx.z;
    const int kblk = blockIdx.y;
    const int kBase = kblk * 128;
    const int qBase = blockIdx.x * 128;
    const _Float16* Kb = Kh + (size_t)b * S_ * D_;
    const _Float16* Qb = Qh + (size_t)b * S_ * D_;

    // staging: LDS chunk f (row r=f>>2, slot c=f&3) holds global chunk c^((r>>1)&3)
    const int f0 = t, f1 = t + 256;
    const int r0 = f0 >> 2, c0 = (f0 & 3) ^ ((r0 >> 1) & 3);
    const int r1 = f1 >> 2, c1 = (f1 & 3) ^ ((r1 >> 1) & 3);

    floatx4 acc[4][4] = {};

    for (int kk = 0; kk < D_; kk += 32) {
        __syncthreads();
        gload16(&Kb[(size_t)(kBase + r0) * D_ + kk + c0 * 8], (char*)Ah + f0 * 16);
        gload16(&Kb[(size_t)(kBase + r1) * D_ + kk + c1 * 8], (char*)Ah + f1 * 16);
        gload16(&Qb[(size_t)(qBase + r0) * D_ + kk + c0 * 8], (char*)Bh + f0 * 16);
        gload16(&Qb[(size_t)(qBase + r1) * D_ + kk + c1 * 8], (char*)Bh + f1 * 16);
        __syncthreads();
        half8 af[4], bf[4];
        #pragma unroll
        for (int mi = 0; mi < 4; ++mi) {
            int row = wrO + mi * 16 + fr;
            int c = (fk >> 3) ^ ((row >> 1) & 3);
            af[mi] = *(half8*)&Ah[row * 32 + c * 8];
        }
        #pragma unroll
        for (int ni = 0; ni < 4; ++ni) {
            int row = wcO + ni * 16 + fr;
            int c = (fk >> 3) ^ ((row >> 1) & 3);
            bf[ni] = *(half8*)&Bh[row * 32 + c * 8];
        }
        #pragma unroll
        for (int mi = 0; mi < 4; ++mi)
            #pragma unroll
            for (int ni = 0; ni < 4; ++ni)
                acc[mi][ni] = mfma16(af[mi], bf[ni], acc[mi][ni]);
    }

    // ---- epilogue: scale, per-q block max over k, e = exp, block sum, stats.
    const float scale = 0.044194173824159216f;  // 1/sqrt(512)
    float pm[4];
    #pragma unroll
    for (int ni = 0; ni < 4; ++ni) {
        float m = -1e30f;
        #pragma unroll
        for (int mi = 0; mi < 4; ++mi)
            #pragma unroll
            for (int j = 0; j < 4; ++j) {
                acc[mi][ni][j] *= scale;
                m = fmaxf(m, acc[mi][ni][j]);
            }
        pm[ni] = m;
    }
    #pragma unroll
    for (int ni = 0; ni < 4; ++ni) {
        pm[ni] = fmaxf(pm[ni], __shfl_xor(pm[ni], 16));
        pm[ni] = fmaxf(pm[ni], __shfl_xor(pm[ni], 32));
    }
    if (l < 16) {
        #pragma unroll
        for (int ni = 0; ni < 4; ++ni) smR[wv][ni * 16 + l] = pm[ni];
    }
    __syncthreads();
    float mb[4], ps[4];
    #pragma unroll
    for (int ni = 0; ni < 4; ++ni)
        mb[ni] = fmaxf(smR[wv & 1][ni * 16 + fr], smR[(wv & 1) + 2][ni * 16 + fr]);
    #pragma unroll
    for (int ni = 0; ni < 4; ++ni) {
        float s = 0.f;
        #pragma unroll
        for (int mi = 0; mi < 4; ++mi)
            #pragma unroll
            for (int j = 0; j < 4; ++j) {
                float e = __expf(acc[mi][ni][j] - mb[ni]);
                acc[mi][ni][j] = e;
                s += e;
            }
        ps[ni] = s;
    }
    #pragma unroll
    for (int ni = 0; ni < 4; ++ni) {
        ps[ni] += __shfl_xor(ps[ni], 16);
        ps[ni] += __shfl_xor(ps[ni], 32);
    }
    __syncthreads();
    if (l < 16) {
        #pragma unroll
        for (int ni = 0; ni < 4; ++ni) smR[wv][ni * 16 + l] = ps[ni];
    }
    __syncthreads();
    if (wv < 2 && l < 16) {
        #pragma unroll
        for (int ni = 0; ni < 4; ++ni) {
            const int ql = wv * 64 + ni * 16 + l;
            float sb = smR[wv][ni * 16 + l] + smR[wv + 2][ni * 16 + l];
            float2 st; st.x = mb[ni]; st.y = sb;
            stats[(size_t)(b * 16 + kblk) * S_ + qBase + ql] = st;
        }
    }

    // ---- store e (fp16) into upper half of each q-row's 8KB output slot
    #pragma unroll
    for (int mi = 0; mi < 4; ++mi) {
        #pragma unroll
        for (int ni = 0; ni < 4; ++ni) {
            const int krow0 = kBase + wrO + mi * 16 + (l >> 4) * 4;
            const int qcol  = qBase + wcO + ni * 16 + fr;
            half4 h = { (_Float16)acc[mi][ni][0], (_Float16)acc[mi][ni][1],
                        (_Float16)acc[mi][ni][2], (_Float16)acc[mi][ni][3] };
            char* p = (char*)Wout + ((size_t)b * S_ + qcol) * (S_ * 4) + 4096 + 2 * krow0;
            *(half4*)p = h;
        }
    }
}

// ---------------------------------------------------------------------------
// Kernel 3: finalize weights + PV.  One 512-thread block owns a 64-q panel.
// Phase A: combine per-kblk stats -> smScale[kblk][q] = exp(m_blk-m)/s.
// Phase B k-loop: stage V tile + e tile (fp16, from upper-half slots) via
// gload16; MFMA on B-frag scaled by smScale in-register; write final fp32
// w = float(e)*scale over the row (covers every byte by loop end).
// ---------------------------------------------------------------------------
__global__ __launch_bounds__(512) void pv2(
    float* __restrict__ Wt, const _Float16* __restrict__ Vt,
    const float2* __restrict__ stats, float* __restrict__ Out)
{
    __shared__ _Float16 Vh[512 * 32];   // V^T tile, linear chunks (src-swizzled)
    __shared__ _Float16 Wh[64 * 32];    // e tile, linear chunks (src-swizzled)
    __shared__ float smM[16][64];
    __shared__ float smS[16][64];
    __shared__ float smScale[16][64];

    const int t = threadIdx.x;
    const int l = t & 63;
    const int wv = t >> 6;               // 0..7 (d-group)
    const int b = blockIdx.y;
    const int qBase = blockIdx.x * 64;
    char* WbB = (char*)Wt + ((size_t)b * S_ + qBase) * (S_ * 4);  // row stride 8192B
    const _Float16* Vb = Vt + (size_t)b * D_ * S_;

    // ---- Phase A: stats combine
    for (int i = t; i < 1024; i += 512) {
        int kb = i >> 6, q = i & 63;
        float2 v = stats[(size_t)(b * 16 + kb) * S_ + qBase + q];
        smM[kb][q] = v.x; smS[kb][q] = v.y;
    }
    __syncthreads();
    if (t < 64) {
        float m = -1e30f;
        #pragma unroll
        for (int kb = 0; kb < 16; ++kb) m = fmaxf(m, smM[kb][t]);
        float s = 0.f;
        #pragma unroll
        for (int kb = 0; kb < 16; ++kb) s += smS[kb][t] * __expf(smM[kb][t] - m);
        const float inv = 1.0f / s;
        #pragma unroll
        for (int kb = 0; kb < 16; ++kb) smScale[kb][t] = __expf(smM[kb][t] - m) * inv;
    }
    __syncthreads();

    const int fr = l & 15;
    const int fk4 = l >> 4;              // chunk index 0..3
    // e staging (waves 0..3 only): 256 chunks of 16B
    const bool doE = (wv < 4);
    const int ge = (wv & 3) * 64 + l;
    const int er = ge >> 2;
    const int es = (ge & 3) ^ ((er >> 1) & 3);
    // w-write path: thread t -> row rw, 4-half group hh
    const int rw = t >> 3, hh = t & 7;
    const int wChunkByte = rw * 64 + (((hh >> 1) ^ ((rw >> 1) & 3)) * 16) + (hh & 1) * 8;

    floatx4 acc[4][4] = {};

    for (int kk = 0; kk < S_; kk += 32) {
        __syncthreads();
        // V^T tile: 2048 chunks, 4 per thread, source-swizzled
        #pragma unroll
        for (int i = 0; i < 4; ++i) {
            int g = t + i * 512;
            int vr = g >> 2;
            int vs = (g & 3) ^ ((vr >> 1) & 3);
            gload16(&Vb[(size_t)vr * S_ + kk + vs * 8], (char*)Vh + (size_t)g * 16);
        }
        // e tile: 64 rows x 32 halves = 256 chunks, waves 0..3
        if (doE)
            gload16(WbB + (size_t)er * 8192 + 4096 + 2 * kk + es * 16,
                    (char*)Wh + ge * 16);
        __syncthreads();

        const int kblk = kk >> 7;
        half8 af[4], bf[4];
        #pragma unroll
        for (int mi = 0; mi < 4; ++mi) {
            int row = wv * 64 + mi * 16 + fr;
            int c = fk4 ^ ((row >> 1) & 3);
            af[mi] = *(half8*)&Vh[row * 32 + c * 8];
        }
        #pragma unroll
        for (int ni = 0; ni < 4; ++ni) {
            int row = ni * 16 + fr;
            int c = fk4 ^ ((row >> 1) & 3);
            bf[ni] = *(half8*)&Wh[row * 32 + c * 8];
            const _Float16 sch = (_Float16)smScale[kblk][row];
            #pragma unroll
            for (int j = 0; j < 8; ++j) bf[ni][j] *= sch;
        }
        #pragma unroll
        for (int mi = 0; mi < 4; ++mi)
            #pragma unroll
            for (int ni = 0; ni < 4; ++ni)
                acc[mi][ni] = mfma16(af[mi], bf[ni], acc[mi][ni]);

        // final fp32 weights write: w = float(e) * scale
        {
            half4 eh = *(half4*)((char*)Wh + wChunkByte);
            const float scw = smScale[kblk][rw];
            float4 w;
            w.x = (float)eh[0] * scw;
            w.y = (float)eh[1] * scw;
            w.z = (float)eh[2] * scw;
            w.w = (float)eh[3] * scw;
            *(float4*)(WbB + (size_t)rw * 8192 + 4 * (kk + hh * 4)) = w;
        }
    }

    #pragma unroll
    for (int mi = 0; mi < 4; ++mi) {
        #pragma unroll
        for (int ni = 0; ni < 4; ++ni) {
            const int d0 = wv * 64 + mi * 16 + (l >> 4) * 4;
            const int q  = qBase + ni * 16 + fr;
            float4 v;
            v.x = acc[mi][ni][0];
            v.y = acc[mi][ni][1];
            v.z = acc[mi][ni][2];
            v.w = acc[mi][ni][3];
            *(float4*)&Out[((size_t)b * S_ + q) * D_ + d0] = v;
        }
    }
}

// ---------------------------------------------------------------------------
extern "C" void kernel_launch(void* const* d_in, const int* in_sizes, int n_in,
                              void* d_out, int out_size, void* d_ws, size_t ws_size,
                              hipStream_t stream)
{
    const float* x  = (const float*)d_in[0];
    const float* Wq = (const float*)d_in[1];
    const float* bq = (const float*)d_in[2];
    const float* Wk = (const float*)d_in[3];
    const float* bk = (const float*)d_in[4];
    const float* Wv = (const float*)d_in[5];
    const float* bv = (const float*)d_in[6];

    float* out = (float*)d_out;                       // [16,2048,512]
    float* wts = out + (size_t)B_ * S_ * D_;          // [16,2048,2048]

    _Float16* Qh = (_Float16*)d_ws;                   // 32 MB
    _Float16* Kh = Qh + (size_t)MTOT * D_;            // 32 MB
    _Float16* Vt = Kh + (size_t)MTOT * D_;            // 32 MB
    float2* stats = (float2*)(Vt + (size_t)MTOT * D_); // 4 MB: [b][kblk][q]{m,s}

    proj_kernel<<<dim3(D_ / 128, MTOT / 128, 3), 256, 0, stream>>>(
        x, Wq, bq, Wk, bk, Wv, bv, Qh, Kh, Vt);
    scores_kernel<<<dim3(S_ / 128, S_ / 128, B_), 256, 0, stream>>>(Qh, Kh, wts, stats);
    pv2<<<dim3(S_ / 64, B_), 512, 0, stream>>>(wts, Vt, stats, out);
}

// Round 6
// 457.782 us; speedup vs baseline: 1.2880x; 1.0328x over previous
//
#include <hip/hip_runtime.h>

#define B_ 16
#define S_ 2048
#define D_ 512
#define MTOT (B_ * S_)

typedef _Float16 half8 __attribute__((ext_vector_type(8)));
typedef _Float16 half4 __attribute__((ext_vector_type(4)));
typedef float floatx4 __attribute__((ext_vector_type(4)));

__device__ __forceinline__ floatx4 mfma16(half8 a, half8 b, floatx4 c) {
    return __builtin_amdgcn_mfma_f32_16x16x32_f16(a, b, c, 0, 0, 0);
}

// async global->LDS, 16B per lane. Per-wave LDS dest must be uniform base + lane*16.
__device__ __forceinline__ void gload16(const void* g, void* l) {
    __builtin_amdgcn_global_load_lds(
        (const __attribute__((address_space(1))) void*)g,
        (__attribute__((address_space(3))) void*)l, 16, 0, 0);
}

// ---------------------------------------------------------------------------
// cvt kernels: fp32 -> fp16, 8 elems/thread.
// x_h and W_h live in the (not yet written) weights output region.
// ---------------------------------------------------------------------------
__global__ __launch_bounds__(256) void cvt_x_kernel(
    const float* __restrict__ src, _Float16* __restrict__ dst)
{
    const size_t i = ((size_t)blockIdx.x * 256 + threadIdx.x) * 8;
    float4 a = *(const float4*)&src[i];
    float4 b = *(const float4*)&src[i + 4];
    half8 h = { (_Float16)a.x, (_Float16)a.y, (_Float16)a.z, (_Float16)a.w,
                (_Float16)b.x, (_Float16)b.y, (_Float16)b.z, (_Float16)b.w };
    *(half8*)&dst[i] = h;
}

__global__ __launch_bounds__(256) void cvt_w_kernel(
    const float* __restrict__ Wq, const float* __restrict__ Wk,
    const float* __restrict__ Wv, _Float16* __restrict__ dst)
{
    const size_t i = ((size_t)blockIdx.x * 256 + threadIdx.x) * 8;
    const int z = (int)(i >> 18);                 // 262144 elems per matrix
    const float* src = (z == 0) ? Wq : ((z == 1) ? Wk : Wv);
    const size_t off = i & 262143;
    float4 a = *(const float4*)&src[off];
    float4 b = *(const float4*)&src[off + 4];
    half8 h = { (_Float16)a.x, (_Float16)a.y, (_Float16)a.z, (_Float16)a.w,
                (_Float16)b.x, (_Float16)b.y, (_Float16)b.z, (_Float16)b.w };
    *(half8*)&dst[i] = h;
}

// ---------------------------------------------------------------------------
// Kernel 1: projection GEMMs from pre-converted fp16 (gload16 staging).
// C[m,e] = sum_d xh[m,d] * W[e,d] + bias[e]
// z==0 -> Qh[m][e]; z==1 -> Kh[m][e] (pre-scaled by 1/sqrt(D));
// z==2 -> Vt[b][e][s] (transposed per batch)
// ---------------------------------------------------------------------------
__global__ __launch_bounds__(256) void proj2_kernel(
    const _Float16* __restrict__ xh, const _Float16* __restrict__ wh3,
    const float* __restrict__ bq, const float* __restrict__ bk,
    const float* __restrict__ bv,
    _Float16* __restrict__ Qh, _Float16* __restrict__ Kh,
    _Float16* __restrict__ Vt)
{
    const int z = blockIdx.z;
    const float* bias = (z == 0) ? bq : ((z == 1) ? bk : bv);
    _Float16* out = (z == 0) ? Qh : ((z == 1) ? Kh : Vt);
    const _Float16* Wz = wh3 + (size_t)z * D_ * D_;

    __shared__ _Float16 Ah[128 * 32];
    __shared__ _Float16 Bh[128 * 32];
    const int t = threadIdx.x;
    const int l = t & 63;
    const int wv = t >> 6;
    const int wrO = (wv >> 1) * 64;
    const int wcO = (wv & 1) * 64;
    const int fr = l & 15;
    const int fk = (l >> 4) * 8;
    const int mBase = blockIdx.y * 128;
    const int eBase = blockIdx.x * 128;

    const int f0 = t, f1 = t + 256;
    const int r0 = f0 >> 2, c0 = (f0 & 3) ^ ((r0 >> 1) & 3);
    const int r1 = f1 >> 2, c1 = (f1 & 3) ^ ((r1 >> 1) & 3);

    floatx4 acc[4][4] = {};

    for (int kk = 0; kk < D_; kk += 32) {
        __syncthreads();
        gload16(&xh[(size_t)(mBase + r0) * D_ + kk + c0 * 8], (char*)Ah + f0 * 16);
        gload16(&xh[(size_t)(mBase + r1) * D_ + kk + c1 * 8], (char*)Ah + f1 * 16);
        gload16(&Wz[(size_t)(eBase + r0) * D_ + kk + c0 * 8], (char*)Bh + f0 * 16);
        gload16(&Wz[(size_t)(eBase + r1) * D_ + kk + c1 * 8], (char*)Bh + f1 * 16);
        __syncthreads();
        half8 af[4], bf[4];
        #pragma unroll
        for (int mi = 0; mi < 4; ++mi) {
            int row = wrO + mi * 16 + fr;
            int c = (fk >> 3) ^ ((row >> 1) & 3);
            af[mi] = *(half8*)&Ah[row * 32 + c * 8];
        }
        #pragma unroll
        for (int ni = 0; ni < 4; ++ni) {
            int row = wcO + ni * 16 + fr;
            int c = (fk >> 3) ^ ((row >> 1) & 3);
            bf[ni] = *(half8*)&Bh[row * 32 + c * 8];
        }
        #pragma unroll
        for (int mi = 0; mi < 4; ++mi)
            #pragma unroll
            for (int ni = 0; ni < 4; ++ni)
                acc[mi][ni] = mfma16(af[mi], bf[ni], acc[mi][ni]);
    }

    const float kscale = (z == 1) ? 0.044194173824159216f : 1.0f;  // 1/sqrt(512)
    #pragma unroll
    for (int mi = 0; mi < 4; ++mi) {
        #pragma unroll
        for (int ni = 0; ni < 4; ++ni) {
            const int col  = eBase + wcO + ni * 16 + fr;
            const int row0 = mBase + wrO + mi * 16 + (l >> 4) * 4;
            const float bv_ = bias[col];
            if (z != 2) {
                #pragma unroll
                for (int j = 0; j < 4; ++j)
                    out[(size_t)(row0 + j) * D_ + col] =
                        (_Float16)((acc[mi][ni][j] + bv_) * kscale);
            } else {
                const int b = row0 >> 11;
                const int s = row0 & (S_ - 1);
                half4 h;
                #pragma unroll
                for (int j = 0; j < 4; ++j) h[j] = (_Float16)(acc[mi][ni][j] + bv_);
                *(half4*)&out[((size_t)b * D_ + col) * S_ + s] = h;
            }
        }
    }
}

// ---------------------------------------------------------------------------
// Kernel 2: scores + per-block softmax partials.  K is pre-scaled, so acc is
// the final scaled score.  Writes e = exp(s - m_blk) as FP16 into the upper
// half of each q-row's 8KB slot in the weights region, plus stats {m,s}.
// ---------------------------------------------------------------------------
__global__ __launch_bounds__(256) void scores_kernel(
    const _Float16* __restrict__ Qh, const _Float16* __restrict__ Kh,
    float* __restrict__ Wout, float2* __restrict__ stats)
{
    __shared__ _Float16 Ah[128 * 32];  // K tile
    __shared__ _Float16 Bh[128 * 32];  // Q tile
    __shared__ float smR[4][64];
    const int t = threadIdx.x;
    const int l = t & 63;
    const int wv = t >> 6;
    const int wrO = (wv >> 1) * 64;
    const int wcO = (wv & 1) * 64;
    const int fr = l & 15;
    const int fk = (l >> 4) * 8;
    const int b = blockIdx.z;
    const int kblk = blockIdx.y;
    const int kBase = kblk * 128;
    const int qBase = blockIdx.x * 128;
    const _Float16* Kb = Kh + (size_t)b * S_ * D_;
    const _Float16* Qb = Qh + (size_t)b * S_ * D_;

    const int f0 = t, f1 = t + 256;
    const int r0 = f0 >> 2, c0 = (f0 & 3) ^ ((r0 >> 1) & 3);
    const int r1 = f1 >> 2, c1 = (f1 & 3) ^ ((r1 >> 1) & 3);

    floatx4 acc[4][4] = {};

    for (int kk = 0; kk < D_; kk += 32) {
        __syncthreads();
        gload16(&Kb[(size_t)(kBase + r0) * D_ + kk + c0 * 8], (char*)Ah + f0 * 16);
        gload16(&Kb[(size_t)(kBase + r1) * D_ + kk + c1 * 8], (char*)Ah + f1 * 16);
        gload16(&Qb[(size_t)(qBase + r0) * D_ + kk + c0 * 8], (char*)Bh + f0 * 16);
        gload16(&Qb[(size_t)(qBase + r1) * D_ + kk + c1 * 8], (char*)Bh + f1 * 16);
        __syncthreads();
        half8 af[4], bf[4];
        #pragma unroll
        for (int mi = 0; mi < 4; ++mi) {
            int row = wrO + mi * 16 + fr;
            int c = (fk >> 3) ^ ((row >> 1) & 3);
            af[mi] = *(half8*)&Ah[row * 32 + c * 8];
        }
        #pragma unroll
        for (int ni = 0; ni < 4; ++ni) {
            int row = wcO + ni * 16 + fr;
            int c = (fk >> 3) ^ ((row >> 1) & 3);
            bf[ni] = *(half8*)&Bh[row * 32 + c * 8];
        }
        #pragma unroll
        for (int mi = 0; mi < 4; ++mi)
            #pragma unroll
            for (int ni = 0; ni < 4; ++ni)
                acc[mi][ni] = mfma16(af[mi], bf[ni], acc[mi][ni]);
    }

    // ---- epilogue: per-q block max over k, e = exp, block sum, stats.
    float pm[4];
    #pragma unroll
    for (int ni = 0; ni < 4; ++ni) {
        float m = -1e30f;
        #pragma unroll
        for (int mi = 0; mi < 4; ++mi)
            #pragma unroll
            for (int j = 0; j < 4; ++j) m = fmaxf(m, acc[mi][ni][j]);
        pm[ni] = m;
    }
    #pragma unroll
    for (int ni = 0; ni < 4; ++ni) {
        pm[ni] = fmaxf(pm[ni], __shfl_xor(pm[ni], 16));
        pm[ni] = fmaxf(pm[ni], __shfl_xor(pm[ni], 32));
    }
    if (l < 16) {
        #pragma unroll
        for (int ni = 0; ni < 4; ++ni) smR[wv][ni * 16 + l] = pm[ni];
    }
    __syncthreads();
    float mb[4], ps[4];
    #pragma unroll
    for (int ni = 0; ni < 4; ++ni)
        mb[ni] = fmaxf(smR[wv & 1][ni * 16 + fr], smR[(wv & 1) + 2][ni * 16 + fr]);
    #pragma unroll
    for (int ni = 0; ni < 4; ++ni) {
        float s = 0.f;
        #pragma unroll
        for (int mi = 0; mi < 4; ++mi)
            #pragma unroll
            for (int j = 0; j < 4; ++j) {
                float e = __expf(acc[mi][ni][j] - mb[ni]);
                acc[mi][ni][j] = e;
                s += e;
            }
        ps[ni] = s;
    }
    #pragma unroll
    for (int ni = 0; ni < 4; ++ni) {
        ps[ni] += __shfl_xor(ps[ni], 16);
        ps[ni] += __shfl_xor(ps[ni], 32);
    }
    __syncthreads();
    if (l < 16) {
        #pragma unroll
        for (int ni = 0; ni < 4; ++ni) smR[wv][ni * 16 + l] = ps[ni];
    }
    __syncthreads();
    if (wv < 2 && l < 16) {
        #pragma unroll
        for (int ni = 0; ni < 4; ++ni) {
            const int ql = wv * 64 + ni * 16 + l;
            float sb = smR[wv][ni * 16 + l] + smR[wv + 2][ni * 16 + l];
            float2 st; st.x = mb[ni]; st.y = sb;
            stats[(size_t)(b * 16 + kblk) * S_ + qBase + ql] = st;
        }
    }

    // ---- store e (fp16) into upper half of each q-row's 8KB output slot
    #pragma unroll
    for (int mi = 0; mi < 4; ++mi) {
        #pragma unroll
        for (int ni = 0; ni < 4; ++ni) {
            const int krow0 = kBase + wrO + mi * 16 + (l >> 4) * 4;
            const int qcol  = qBase + wcO + ni * 16 + fr;
            half4 h = { (_Float16)acc[mi][ni][0], (_Float16)acc[mi][ni][1],
                        (_Float16)acc[mi][ni][2], (_Float16)acc[mi][ni][3] };
            char* p = (char*)Wout + ((size_t)b * S_ + qcol) * (S_ * 4) + 4096 + 2 * krow0;
            *(half4*)p = h;
        }
    }
}

// ---------------------------------------------------------------------------
// Kernel 3: PV only (no global stores in the k-loop).
// out[b][q][d] = sum_k e[b,q,k]*smScale[kblk][q] * V[b,k,d]
// ---------------------------------------------------------------------------
__global__ __launch_bounds__(512) void pv3(
    const float* __restrict__ Wt, const _Float16* __restrict__ Vt,
    const float2* __restrict__ stats, float* __restrict__ Out)
{
    __shared__ _Float16 Vh[512 * 32];
    __shared__ _Float16 Wh[64 * 32];
    __shared__ float smM[16][64];
    __shared__ float smS[16][64];
    __shared__ float smScale[16][64];

    const int t = threadIdx.x;
    const int l = t & 63;
    const int wv = t >> 6;
    const int b = blockIdx.y;
    const int qBase = blockIdx.x * 64;
    const char* WbB = (const char*)Wt + ((size_t)b * S_ + qBase) * (S_ * 4);
    const _Float16* Vb = Vt + (size_t)b * D_ * S_;

    for (int i = t; i < 1024; i += 512) {
        int kb = i >> 6, q = i & 63;
        float2 v = stats[(size_t)(b * 16 + kb) * S_ + qBase + q];
        smM[kb][q] = v.x; smS[kb][q] = v.y;
    }
    __syncthreads();
    if (t < 64) {
        float m = -1e30f;
        #pragma unroll
        for (int kb = 0; kb < 16; ++kb) m = fmaxf(m, smM[kb][t]);
        float s = 0.f;
        #pragma unroll
        for (int kb = 0; kb < 16; ++kb) s += smS[kb][t] * __expf(smM[kb][t] - m);
        const float inv = 1.0f / s;
        #pragma unroll
        for (int kb = 0; kb < 16; ++kb) smScale[kb][t] = __expf(smM[kb][t] - m) * inv;
    }
    __syncthreads();

    const int fr = l & 15;
    const int fk4 = l >> 4;
    const bool doE = (wv < 4);
    const int ge = (wv & 3) * 64 + l;
    const int er = ge >> 2;
    const int es = (ge & 3) ^ ((er >> 1) & 3);

    floatx4 acc[4][4] = {};

    for (int kk = 0; kk < S_; kk += 32) {
        __syncthreads();
        #pragma unroll
        for (int i = 0; i < 4; ++i) {
            int g = t + i * 512;
            int vr = g >> 2;
            int vs = (g & 3) ^ ((vr >> 1) & 3);
            gload16(&Vb[(size_t)vr * S_ + kk + vs * 8], (char*)Vh + (size_t)g * 16);
        }
        if (doE)
            gload16(WbB + (size_t)er * 8192 + 4096 + 2 * kk + es * 16,
                    (char*)Wh + ge * 16);
        __syncthreads();

        const int kblk = kk >> 7;
        half8 af[4], bf[4];
        #pragma unroll
        for (int mi = 0; mi < 4; ++mi) {
            int row = wv * 64 + mi * 16 + fr;
            int c = fk4 ^ ((row >> 1) & 3);
            af[mi] = *(half8*)&Vh[row * 32 + c * 8];
        }
        #pragma unroll
        for (int ni = 0; ni < 4; ++ni) {
            int row = ni * 16 + fr;
            int c = fk4 ^ ((row >> 1) & 3);
            bf[ni] = *(half8*)&Wh[row * 32 + c * 8];
            const _Float16 sch = (_Float16)smScale[kblk][row];
            #pragma unroll
            for (int j = 0; j < 8; ++j) bf[ni][j] *= sch;
        }
        #pragma unroll
        for (int mi = 0; mi < 4; ++mi)
            #pragma unroll
            for (int ni = 0; ni < 4; ++ni)
                acc[mi][ni] = mfma16(af[mi], bf[ni], acc[mi][ni]);
    }

    #pragma unroll
    for (int mi = 0; mi < 4; ++mi) {
        #pragma unroll
        for (int ni = 0; ni < 4; ++ni) {
            const int d0 = wv * 64 + mi * 16 + (l >> 4) * 4;
            const int q  = qBase + ni * 16 + fr;
            float4 v;
            v.x = acc[mi][ni][0];
            v.y = acc[mi][ni][1];
            v.z = acc[mi][ni][2];
            v.w = acc[mi][ni][3];
            *(float4*)&Out[((size_t)b * S_ + q) * D_ + d0] = v;
        }
    }
}

// ---------------------------------------------------------------------------
// Kernel 4: weights finalize (pure streaming).  wave owns whole q-rows:
// read e fp16 (upper half of row), scale, write full fp32 row in place.
// ---------------------------------------------------------------------------
__global__ __launch_bounds__(256) void wfin(
    float* __restrict__ Wt, const float2* __restrict__ stats)
{
    const int t = threadIdx.x;
    const int l = t & 63;
    const int wv = t >> 6;
    const int wid = blockIdx.x * 4 + wv;          // 0..8191

    for (int rr = 0; rr < 4; ++rr) {
        const int row = wid + rr * 8192;          // 0..32767
        const int b = row >> 11, q = row & (S_ - 1);

        float mkb[16], skb[16];
        float m = -1e30f;
        #pragma unroll
        for (int kb = 0; kb < 16; ++kb) {
            float2 st = stats[(size_t)(b * 16 + kb) * S_ + q];
            mkb[kb] = st.x; skb[kb] = st.y;
            m = fmaxf(m, st.x);
        }
        float s = 0.f;
        #pragma unroll
        for (int kb = 0; kb < 16; ++kb) {
            mkb[kb] = __expf(mkb[kb] - m);
            s += skb[kb] * mkb[kb];
        }
        const float inv = 1.0f / s;

        char* rowp = (char*)Wt + (size_t)row * (S_ * 4);
        half4 eh[8];
        #pragma unroll
        for (int j = 0; j < 8; ++j)
            eh[j] = *(const half4*)(rowp + 4096 + j * 512 + 8 * l);
        float4 w[8];
        #pragma unroll
        for (int j = 0; j < 8; ++j) {
            const float sc = mkb[2 * j + (l >> 5)] * inv;
            w[j].x = (float)eh[j][0] * sc;
            w[j].y = (float)eh[j][1] * sc;
            w[j].z = (float)eh[j][2] * sc;
            w[j].w = (float)eh[j][3] * sc;
        }
        // all e loads must complete before any in-place overwrite
        asm volatile("s_waitcnt vmcnt(0)" ::: "memory");
        #pragma unroll
        for (int j = 0; j < 8; ++j)
            *(float4*)(rowp + j * 1024 + 16 * l) = w[j];
    }
}

// ---------------------------------------------------------------------------
extern "C" void kernel_launch(void* const* d_in, const int* in_sizes, int n_in,
                              void* d_out, int out_size, void* d_ws, size_t ws_size,
                              hipStream_t stream)
{
    const float* x  = (const float*)d_in[0];
    const float* Wq = (const float*)d_in[1];
    const float* bq = (const float*)d_in[2];
    const float* Wk = (const float*)d_in[3];
    const float* bk = (const float*)d_in[4];
    const float* Wv = (const float*)d_in[5];
    const float* bv = (const float*)d_in[6];

    float* out = (float*)d_out;                       // [16,2048,512]
    float* wts = out + (size_t)B_ * S_ * D_;          // [16,2048,2048]

    _Float16* Qh = (_Float16*)d_ws;                   // 32 MB
    _Float16* Kh = Qh + (size_t)MTOT * D_;            // 32 MB
    _Float16* Vt = Kh + (size_t)MTOT * D_;            // 32 MB
    float2* stats = (float2*)(Vt + (size_t)MTOT * D_); // 4 MB

    // fp16 scratch inside the weights output region (dead until scores runs)
    _Float16* xh  = (_Float16*)wts;                   // 33.5 MB
    _Float16* wh3 = xh + (size_t)MTOT * D_;           // 1.5 MB

    cvt_x_kernel<<<MTOT * D_ / (256 * 8), 256, 0, stream>>>(x, xh);
    cvt_w_kernel<<<3 * D_ * D_ / (256 * 8), 256, 0, stream>>>(Wq, Wk, Wv, wh3);
    proj2_kernel<<<dim3(D_ / 128, MTOT / 128, 3), 256, 0, stream>>>(
        xh, wh3, bq, bk, bv, Qh, Kh, Vt);
    scores_kernel<<<dim3(S_ / 128, S_ / 128, B_), 256, 0, stream>>>(Qh, Kh, wts, stats);
    pv3<<<dim3(S_ / 64, B_), 512, 0, stream>>>(wts, Vt, stats, out);
    wfin<<<2048, 256, 0, stream>>>(wts, stats);
}

// Round 7
// 425.730 us; speedup vs baseline: 1.3849x; 1.0753x over previous
//
#include <hip/hip_runtime.h>

#define B_ 16
#define S_ 2048
#define D_ 512
#define MTOT (B_ * S_)

typedef _Float16 half8 __attribute__((ext_vector_type(8)));
typedef _Float16 half4 __attribute__((ext_vector_type(4)));
typedef float floatx4 __attribute__((ext_vector_type(4)));

__device__ __forceinline__ floatx4 mfma16(half8 a, half8 b, floatx4 c) {
    return __builtin_amdgcn_mfma_f32_16x16x32_f16(a, b, c, 0, 0, 0);
}

// async global->LDS, 16B per lane. Per-wave LDS dest must be uniform base + lane*16.
__device__ __forceinline__ void gload16(const void* g, void* l) {
    __builtin_amdgcn_global_load_lds(
        (const __attribute__((address_space(1))) void*)g,
        (__attribute__((address_space(3))) void*)l, 16, 0, 0);
}

// ---------------------------------------------------------------------------
// cvt kernels: fp32 -> fp16, 8 elems/thread.
// ---------------------------------------------------------------------------
__global__ __launch_bounds__(256) void cvt_x_kernel(
    const float* __restrict__ src, _Float16* __restrict__ dst)
{
    const size_t i = ((size_t)blockIdx.x * 256 + threadIdx.x) * 8;
    float4 a = *(const float4*)&src[i];
    float4 b = *(const float4*)&src[i + 4];
    half8 h = { (_Float16)a.x, (_Float16)a.y, (_Float16)a.z, (_Float16)a.w,
                (_Float16)b.x, (_Float16)b.y, (_Float16)b.z, (_Float16)b.w };
    *(half8*)&dst[i] = h;
}

__global__ __launch_bounds__(256) void cvt_w_kernel(
    const float* __restrict__ Wq, const float* __restrict__ Wk,
    const float* __restrict__ Wv, _Float16* __restrict__ dst)
{
    const size_t i = ((size_t)blockIdx.x * 256 + threadIdx.x) * 8;
    const int z = (int)(i >> 18);                 // 262144 elems per matrix
    const float* src = (z == 0) ? Wq : ((z == 1) ? Wk : Wv);
    const size_t off = i & 262143;
    float4 a = *(const float4*)&src[off];
    float4 b = *(const float4*)&src[off + 4];
    half8 h = { (_Float16)a.x, (_Float16)a.y, (_Float16)a.z, (_Float16)a.w,
                (_Float16)b.x, (_Float16)b.y, (_Float16)b.z, (_Float16)b.w };
    *(half8*)&dst[i] = h;
}

// ---------------------------------------------------------------------------
// Kernel 1: projection GEMMs, 2-phase double-buffered staging.
// z==0 -> Qh[m][e]; z==1 -> Kh[m][e] (pre-scaled 1/sqrt(D)); z==2 -> Vt[b][e][s]
// ---------------------------------------------------------------------------
__global__ __launch_bounds__(256) void proj2_kernel(
    const _Float16* __restrict__ xh, const _Float16* __restrict__ wh3,
    const float* __restrict__ bq, const float* __restrict__ bk,
    const float* __restrict__ bv,
    _Float16* __restrict__ Qh, _Float16* __restrict__ Kh,
    _Float16* __restrict__ Vt)
{
    const int z = blockIdx.z;
    const float* bias = (z == 0) ? bq : ((z == 1) ? bk : bv);
    _Float16* out = (z == 0) ? Qh : ((z == 1) ? Kh : Vt);
    const _Float16* Wz = wh3 + (size_t)z * D_ * D_;

    __shared__ _Float16 Ah[2][128 * 32];
    __shared__ _Float16 Bh[2][128 * 32];
    const int t = threadIdx.x;
    const int l = t & 63;
    const int wv = t >> 6;
    const int wrO = (wv >> 1) * 64;
    const int wcO = (wv & 1) * 64;
    const int fr = l & 15;
    const int fk = (l >> 4) * 8;
    const int mBase = blockIdx.y * 128;
    const int eBase = blockIdx.x * 128;

    const int f0 = t, f1 = t + 256;
    const int r0 = f0 >> 2, c0 = (f0 & 3) ^ ((r0 >> 1) & 3);
    const int r1 = f1 >> 2, c1 = (f1 & 3) ^ ((r1 >> 1) & 3);

#define STAGE_PROJ(buf, kk) do {                                               \
    gload16(&xh[(size_t)(mBase + r0) * D_ + (kk) + c0 * 8], (char*)Ah[buf] + f0 * 16); \
    gload16(&xh[(size_t)(mBase + r1) * D_ + (kk) + c1 * 8], (char*)Ah[buf] + f1 * 16); \
    gload16(&Wz[(size_t)(eBase + r0) * D_ + (kk) + c0 * 8], (char*)Bh[buf] + f0 * 16); \
    gload16(&Wz[(size_t)(eBase + r1) * D_ + (kk) + c1 * 8], (char*)Bh[buf] + f1 * 16); \
} while (0)

    floatx4 acc[4][4] = {};

    STAGE_PROJ(0, 0);
    __syncthreads();
    int cur = 0;
    for (int step = 0; step < 16; ++step) {
        const int kk = step * 32;
        if (step < 15) STAGE_PROJ(cur ^ 1, kk + 32);
        half8 af[4], bf[4];
        #pragma unroll
        for (int mi = 0; mi < 4; ++mi) {
            int row = wrO + mi * 16 + fr;
            int c = (fk >> 3) ^ ((row >> 1) & 3);
            af[mi] = *(half8*)&Ah[cur][row * 32 + c * 8];
        }
        #pragma unroll
        for (int ni = 0; ni < 4; ++ni) {
            int row = wcO + ni * 16 + fr;
            int c = (fk >> 3) ^ ((row >> 1) & 3);
            bf[ni] = *(half8*)&Bh[cur][row * 32 + c * 8];
        }
        #pragma unroll
        for (int mi = 0; mi < 4; ++mi)
            #pragma unroll
            for (int ni = 0; ni < 4; ++ni)
                acc[mi][ni] = mfma16(af[mi], bf[ni], acc[mi][ni]);
        __syncthreads();
        cur ^= 1;
    }
#undef STAGE_PROJ

    const float kscale = (z == 1) ? 0.044194173824159216f : 1.0f;  // 1/sqrt(512)
    #pragma unroll
    for (int mi = 0; mi < 4; ++mi) {
        #pragma unroll
        for (int ni = 0; ni < 4; ++ni) {
            const int col  = eBase + wcO + ni * 16 + fr;
            const int row0 = mBase + wrO + mi * 16 + (l >> 4) * 4;
            const float bv_ = bias[col];
            if (z != 2) {
                #pragma unroll
                for (int j = 0; j < 4; ++j)
                    out[(size_t)(row0 + j) * D_ + col] =
                        (_Float16)((acc[mi][ni][j] + bv_) * kscale);
            } else {
                const int b = row0 >> 11;
                const int s = row0 & (S_ - 1);
                half4 h;
                #pragma unroll
                for (int j = 0; j < 4; ++j) h[j] = (_Float16)(acc[mi][ni][j] + bv_);
                *(half4*)&out[((size_t)b * D_ + col) * S_ + s] = h;
            }
        }
    }
}

// ---------------------------------------------------------------------------
// Kernel 2: scores + per-block softmax partials, 2-phase double-buffered.
// Writes e = exp(s - m_blk) fp16 into upper half of each q-row's 8KB slot,
// plus per-(kblk,q) stats {m_blk, s_blk}.
// ---------------------------------------------------------------------------
__global__ __launch_bounds__(256) void scores_kernel(
    const _Float16* __restrict__ Qh, const _Float16* __restrict__ Kh,
    float* __restrict__ Wout, float2* __restrict__ stats)
{
    __shared__ _Float16 Ah[2][128 * 32];  // K tile
    __shared__ _Float16 Bh[2][128 * 32];  // Q tile
    __shared__ float smR[4][64];
    const int t = threadIdx.x;
    const int l = t & 63;
    const int wv = t >> 6;
    const int wrO = (wv >> 1) * 64;
    const int wcO = (wv & 1) * 64;
    const int fr = l & 15;
    const int fk = (l >> 4) * 8;
    const int b = blockIdx.z;
    const int kblk = blockIdx.y;
    const int kBase = kblk * 128;
    const int qBase = blockIdx.x * 128;
    const _Float16* Kb = Kh + (size_t)b * S_ * D_;
    const _Float16* Qb = Qh + (size_t)b * S_ * D_;

    const int f0 = t, f1 = t + 256;
    const int r0 = f0 >> 2, c0 = (f0 & 3) ^ ((r0 >> 1) & 3);
    const int r1 = f1 >> 2, c1 = (f1 & 3) ^ ((r1 >> 1) & 3);

#define STAGE_SC(buf, kk) do {                                                 \
    gload16(&Kb[(size_t)(kBase + r0) * D_ + (kk) + c0 * 8], (char*)Ah[buf] + f0 * 16); \
    gload16(&Kb[(size_t)(kBase + r1) * D_ + (kk) + c1 * 8], (char*)Ah[buf] + f1 * 16); \
    gload16(&Qb[(size_t)(qBase + r0) * D_ + (kk) + c0 * 8], (char*)Bh[buf] + f0 * 16); \
    gload16(&Qb[(size_t)(qBase + r1) * D_ + (kk) + c1 * 8], (char*)Bh[buf] + f1 * 16); \
} while (0)

    floatx4 acc[4][4] = {};

    STAGE_SC(0, 0);
    __syncthreads();
    int cur = 0;
    for (int step = 0; step < 16; ++step) {
        const int kk = step * 32;
        if (step < 15) STAGE_SC(cur ^ 1, kk + 32);
        half8 af[4], bf[4];
        #pragma unroll
        for (int mi = 0; mi < 4; ++mi) {
            int row = wrO + mi * 16 + fr;
            int c = (fk >> 3) ^ ((row >> 1) & 3);
            af[mi] = *(half8*)&Ah[cur][row * 32 + c * 8];
        }
        #pragma unroll
        for (int ni = 0; ni < 4; ++ni) {
            int row = wcO + ni * 16 + fr;
            int c = (fk >> 3) ^ ((row >> 1) & 3);
            bf[ni] = *(half8*)&Bh[cur][row * 32 + c * 8];
        }
        #pragma unroll
        for (int mi = 0; mi < 4; ++mi)
            #pragma unroll
            for (int ni = 0; ni < 4; ++ni)
                acc[mi][ni] = mfma16(af[mi], bf[ni], acc[mi][ni]);
        __syncthreads();
        cur ^= 1;
    }
#undef STAGE_SC

    // ---- epilogue: per-q block max over k, e = exp, block sum, stats.
    float pm[4];
    #pragma unroll
    for (int ni = 0; ni < 4; ++ni) {
        float m = -1e30f;
        #pragma unroll
        for (int mi = 0; mi < 4; ++mi)
            #pragma unroll
            for (int j = 0; j < 4; ++j) m = fmaxf(m, acc[mi][ni][j]);
        pm[ni] = m;
    }
    #pragma unroll
    for (int ni = 0; ni < 4; ++ni) {
        pm[ni] = fmaxf(pm[ni], __shfl_xor(pm[ni], 16));
        pm[ni] = fmaxf(pm[ni], __shfl_xor(pm[ni], 32));
    }
    if (l < 16) {
        #pragma unroll
        for (int ni = 0; ni < 4; ++ni) smR[wv][ni * 16 + l] = pm[ni];
    }
    __syncthreads();
    float mb[4], ps[4];
    #pragma unroll
    for (int ni = 0; ni < 4; ++ni)
        mb[ni] = fmaxf(smR[wv & 1][ni * 16 + fr], smR[(wv & 1) + 2][ni * 16 + fr]);
    #pragma unroll
    for (int ni = 0; ni < 4; ++ni) {
        float s = 0.f;
        #pragma unroll
        for (int mi = 0; mi < 4; ++mi)
            #pragma unroll
            for (int j = 0; j < 4; ++j) {
                float e = __expf(acc[mi][ni][j] - mb[ni]);
                acc[mi][ni][j] = e;
                s += e;
            }
        ps[ni] = s;
    }
    #pragma unroll
    for (int ni = 0; ni < 4; ++ni) {
        ps[ni] += __shfl_xor(ps[ni], 16);
        ps[ni] += __shfl_xor(ps[ni], 32);
    }
    __syncthreads();
    if (l < 16) {
        #pragma unroll
        for (int ni = 0; ni < 4; ++ni) smR[wv][ni * 16 + l] = ps[ni];
    }
    __syncthreads();
    if (wv < 2 && l < 16) {
        #pragma unroll
        for (int ni = 0; ni < 4; ++ni) {
            const int ql = wv * 64 + ni * 16 + l;
            float sb = smR[wv][ni * 16 + l] + smR[wv + 2][ni * 16 + l];
            float2 st; st.x = mb[ni]; st.y = sb;
            stats[(size_t)(b * 16 + kblk) * S_ + qBase + ql] = st;
        }
    }

    #pragma unroll
    for (int mi = 0; mi < 4; ++mi) {
        #pragma unroll
        for (int ni = 0; ni < 4; ++ni) {
            const int krow0 = kBase + wrO + mi * 16 + (l >> 4) * 4;
            const int qcol  = qBase + wcO + ni * 16 + fr;
            half4 h = { (_Float16)acc[mi][ni][0], (_Float16)acc[mi][ni][1],
                        (_Float16)acc[mi][ni][2], (_Float16)acc[mi][ni][3] };
            char* p = (char*)Wout + ((size_t)b * S_ + qcol) * (S_ * 4) + 4096 + 2 * krow0;
            *(half4*)p = h;
        }
    }
}

// ---------------------------------------------------------------------------
// Kernel 3: PV + fused fp32 weights write, 2-phase double-buffered.
// out[b][q][d] = sum_k e[b,q,k]*smScale[kblk][q] * V[b,k,d]
// w[b][q][k] = float(e) * smScale  (written in place over the e rows)
// ---------------------------------------------------------------------------
__global__ __launch_bounds__(512) void pv4(
    float* __restrict__ Wt, const _Float16* __restrict__ Vt,
    const float2* __restrict__ stats, float* __restrict__ Out)
{
    __shared__ _Float16 Vh[2][512 * 32];   // 64KB
    __shared__ _Float16 Wh[2][64 * 32];    // 8KB
    __shared__ float smScale[16][64];      // 4KB

    const int t = threadIdx.x;
    const int l = t & 63;
    const int wv = t >> 6;
    const int b = blockIdx.y;
    const int qBase = blockIdx.x * 64;
    char* WbB = (char*)Wt + ((size_t)b * S_ + qBase) * (S_ * 4);  // row stride 8192B
    const _Float16* Vb = Vt + (size_t)b * D_ * S_;

    const int fr = l & 15;
    const int fk4 = l >> 4;
    const bool doE = (wv < 4);
    const int ge = (wv & 3) * 64 + l;
    const int er = ge >> 2;
    const int es = (ge & 3) ^ ((er >> 1) & 3);
    const int rw = t >> 3, hh = t & 7;
    const int wChunkByte = rw * 64 + (((hh >> 1) ^ ((rw >> 1) & 3)) * 16) + (hh & 1) * 8;

#define STAGE_PV(buf, kk) do {                                                 \
    _Pragma("unroll")                                                          \
    for (int i_ = 0; i_ < 4; ++i_) {                                           \
        int g_ = t + i_ * 512;                                                 \
        int vr_ = g_ >> 2;                                                     \
        int vs_ = (g_ & 3) ^ ((vr_ >> 1) & 3);                                 \
        gload16(&Vb[(size_t)vr_ * S_ + (kk) + vs_ * 8], (char*)Vh[buf] + (size_t)g_ * 16); \
    }                                                                          \
    if (doE)                                                                   \
        gload16(WbB + (size_t)er * 8192 + 4096 + 2 * (kk) + es * 16,           \
                (char*)Wh[buf] + ge * 16);                                     \
} while (0)

    floatx4 acc[4][4] = {};

    STAGE_PV(0, 0);

    // ---- Phase A: per-q softmax stats combine, wave 0 only, into smScale
    if (t < 64) {
        float mkb[16], skb[16];
        float m = -1e30f;
        #pragma unroll
        for (int kb = 0; kb < 16; ++kb) {
            float2 st = stats[(size_t)(b * 16 + kb) * S_ + qBase + t];
            mkb[kb] = st.x; skb[kb] = st.y;
            m = fmaxf(m, st.x);
        }
        float s = 0.f;
        #pragma unroll
        for (int kb = 0; kb < 16; ++kb) {
            mkb[kb] = __expf(mkb[kb] - m);
            s += skb[kb] * mkb[kb];
        }
        const float inv = 1.0f / s;
        #pragma unroll
        for (int kb = 0; kb < 16; ++kb) smScale[kb][t] = mkb[kb] * inv;
    }
    __syncthreads();

    int cur = 0;
    for (int step = 0; step < 64; ++step) {
        const int kk = step * 32;
        if (step < 63) STAGE_PV(cur ^ 1, kk + 32);
        const int kblk = kk >> 7;
        half8 af[4], bf[4];
        #pragma unroll
        for (int mi = 0; mi < 4; ++mi) {
            int row = wv * 64 + mi * 16 + fr;
            int c = fk4 ^ ((row >> 1) & 3);
            af[mi] = *(half8*)&Vh[cur][row * 32 + c * 8];
        }
        #pragma unroll
        for (int ni = 0; ni < 4; ++ni) {
            int row = ni * 16 + fr;
            int c = fk4 ^ ((row >> 1) & 3);
            bf[ni] = *(half8*)&Wh[cur][row * 32 + c * 8];
            const _Float16 sch = (_Float16)smScale[kblk][row];
            #pragma unroll
            for (int j = 0; j < 8; ++j) bf[ni][j] *= sch;
        }
        // fused fp32 weights write: w = float(e) * scale  (issues before MFMA,
        // retires during the MFMA phase)
        {
            half4 eh = *(half4*)((char*)Wh[cur] + wChunkByte);
            const float scw = smScale[kblk][rw];
            float4 w;
            w.x = (float)eh[0] * scw;
            w.y = (float)eh[1] * scw;
            w.z = (float)eh[2] * scw;
            w.w = (float)eh[3] * scw;
            *(float4*)(WbB + (size_t)rw * 8192 + 4 * (kk + hh * 4)) = w;
        }
        #pragma unroll
        for (int mi = 0; mi < 4; ++mi)
            #pragma unroll
            for (int ni = 0; ni < 4; ++ni)
                acc[mi][ni] = mfma16(af[mi], bf[ni], acc[mi][ni]);
        __syncthreads();
        cur ^= 1;
    }
#undef STAGE_PV

    #pragma unroll
    for (int mi = 0; mi < 4; ++mi) {
        #pragma unroll
        for (int ni = 0; ni < 4; ++ni) {
            const int d0 = wv * 64 + mi * 16 + (l >> 4) * 4;
            const int q  = qBase + ni * 16 + fr;
            float4 v;
            v.x = acc[mi][ni][0];
            v.y = acc[mi][ni][1];
            v.z = acc[mi][ni][2];
            v.w = acc[mi][ni][3];
            *(float4*)&Out[((size_t)b * S_ + q) * D_ + d0] = v;
        }
    }
}

// ---------------------------------------------------------------------------
extern "C" void kernel_launch(void* const* d_in, const int* in_sizes, int n_in,
                              void* d_out, int out_size, void* d_ws, size_t ws_size,
                              hipStream_t stream)
{
    const float* x  = (const float*)d_in[0];
    const float* Wq = (const float*)d_in[1];
    const float* bq = (const float*)d_in[2];
    const float* Wk = (const float*)d_in[3];
    const float* bk = (const float*)d_in[4];
    const float* Wv = (const float*)d_in[5];
    const float* bv = (const float*)d_in[6];

    float* out = (float*)d_out;                       // [16,2048,512]
    float* wts = out + (size_t)B_ * S_ * D_;          // [16,2048,2048]

    _Float16* Qh = (_Float16*)d_ws;                   // 32 MB
    _Float16* Kh = Qh + (size_t)MTOT * D_;            // 32 MB
    _Float16* Vt = Kh + (size_t)MTOT * D_;            // 32 MB
    float2* stats = (float2*)(Vt + (size_t)MTOT * D_); // 4 MB

    // fp16 scratch inside the weights output region (dead until scores runs)
    _Float16* xh  = (_Float16*)wts;                   // 33.5 MB
    _Float16* wh3 = xh + (size_t)MTOT * D_;           // 1.5 MB

    cvt_x_kernel<<<MTOT * D_ / (256 * 8), 256, 0, stream>>>(x, xh);
    cvt_w_kernel<<<3 * D_ * D_ / (256 * 8), 256, 0, stream>>>(Wq, Wk, Wv, wh3);
    proj2_kernel<<<dim3(D_ / 128, MTOT / 128, 3), 256, 0, stream>>>(
        xh, wh3, bq, bk, bv, Qh, Kh, Vt);
    scores_kernel<<<dim3(S_ / 128, S_ / 128, B_), 256, 0, stream>>>(Qh, Kh, wts, stats);
    pv4<<<dim3(S_ / 64, B_), 512, 0, stream>>>(wts, Vt, stats, out);
}